// Round 1
// baseline (688.478 us; speedup 1.0000x reference)
//
#include <hip/hip_runtime.h>

// ---------------------------------------------------------------------------
// MSCrossAttnBlock on MI355X (gfx950).
// B=4, E=32, LQ=1024, D=1024, NH=16, DH=64, NP=4. All levels are 32x32.
// Pipeline:
//   q_ln   = LN(src3)                      -> bf16
//   f_ln   = LN(concat(src0..3))           -> bf16
//   val_ca = f_ln @ ca_vw^T + vb           -> bf16   (M=16384,N=1024)
//   off_ca = q_ln @ ca_ow^T + ob           -> f32    (M=4096, N=512)
//   aw_ca  = softmax(q_ln @ ca_aw^T + ab)  -> f32    (M=4096, N=256, sm w=16)
//   samp   = ms_deform_sample(val_ca, ...) -> bf16
//   attn   = samp @ ca_pw^T + pb           -> f32
//   attn1  = LN(attn)                      -> bf16
//   val_sa/off_sa/aw_sa, samp_sa, attn2 similarly (nLev=1)
//   out    = src3 + g1*(attn + g2*attn2)
// ---------------------------------------------------------------------------

#define DEV __device__ __forceinline__

typedef float f32x4 __attribute__((ext_vector_type(4)));
typedef __bf16 bf16x8 __attribute__((ext_vector_type(8)));

DEV unsigned short f2bf(float f) {
  union { float f; unsigned u; } a; a.f = f;
  unsigned r = a.u + 0x7fffu + ((a.u >> 16) & 1u);
  return (unsigned short)(r >> 16);
}
DEV float bf2f(unsigned short h) {
  union { unsigned u; float f; } a; a.u = ((unsigned)h) << 16;
  return a.f;
}

// ---------------- weight fp32 -> bf16 conversion (vector x4) ---------------
__global__ void f2bf_kernel(const float* __restrict__ x,
                            unsigned short* __restrict__ y, int n4) {
  int i = blockIdx.x * blockDim.x + threadIdx.x;
  if (i >= n4) return;
  float4 v = ((const float4*)x)[i];
  unsigned short* o = y + i * 4;
  o[0] = f2bf(v.x); o[1] = f2bf(v.y); o[2] = f2bf(v.z); o[3] = f2bf(v.w);
}

// ---------------- LayerNorm (D=1024), one block (256 thr) per row ----------
// out row = (row>>10)*out_bstride + out_base + (row&1023)
__global__ __launch_bounds__(256) void ln_bf16_kernel(
    const float* __restrict__ x, const float* __restrict__ g,
    const float* __restrict__ b, unsigned short* __restrict__ out,
    int out_base, int out_bstride) {
  int row = blockIdx.x;
  int batch = row >> 10, r = row & 1023;
  const float* xr = x + (size_t)row * 1024;
  float4 v = ((const float4*)xr)[threadIdx.x];
  float s  = v.x + v.y + v.z + v.w;
  float s2 = v.x*v.x + v.y*v.y + v.z*v.z + v.w*v.w;
  #pragma unroll
  for (int o = 32; o; o >>= 1) { s += __shfl_down(s, o); s2 += __shfl_down(s2, o); }
  __shared__ float red[8];
  int wave = threadIdx.x >> 6, lane = threadIdx.x & 63;
  if (lane == 0) { red[wave] = s; red[4 + wave] = s2; }
  __syncthreads();
  if (threadIdx.x == 0) {
    float ts  = red[0] + red[1] + red[2] + red[3];
    float ts2 = red[4] + red[5] + red[6] + red[7];
    float mean = ts * (1.f / 1024.f);
    float var  = ts2 * (1.f / 1024.f) - mean * mean;
    red[0] = mean; red[1] = rsqrtf(var + 1e-6f);
  }
  __syncthreads();
  float mean = red[0], rstd = red[1];
  float4 gg = ((const float4*)g)[threadIdx.x];
  float4 bb = ((const float4*)b)[threadIdx.x];
  int orow = batch * out_bstride + out_base + r;
  unsigned short* op = out + (size_t)orow * 1024 + threadIdx.x * 4;
  op[0] = f2bf((v.x - mean) * rstd * gg.x + bb.x);
  op[1] = f2bf((v.y - mean) * rstd * gg.y + bb.y);
  op[2] = f2bf((v.z - mean) * rstd * gg.z + bb.z);
  op[3] = f2bf((v.w - mean) * rstd * gg.w + bb.w);
}

// ---------------- bf16 MFMA GEMM: C[M,N] = A[M,K] @ W[N,K]^T + bias --------
// 256 threads = 4 waves (2x2), wave tile WMxWN of 16x16x32 fragments.
// A-frag: lane holds A[m=lane&15][k=(lane>>4)*8+j]; B-frag symmetric (W rows).
// C/D: col=lane&15, row=(lane>>4)*4+reg.
template <int BM, int BN, bool OUT_BF16>
__global__ __launch_bounds__(256) void gemm_bf16(
    const unsigned short* __restrict__ A, const unsigned short* __restrict__ W,
    const float* __restrict__ bias, void* __restrict__ Cout,
    int M, int N, int K) {
  constexpr int BK = 32;
  constexpr int WMT = BM / 2, WNT = BN / 2;
  constexpr int MF = WMT / 16, NF = WNT / 16;
  constexpr int LDSK = BK + 8;  // pad 16B to spread banks
  __shared__ __align__(16) unsigned short sA[BM * LDSK];
  __shared__ __align__(16) unsigned short sB[BN * LDSK];
  const int tid = threadIdx.x;
  const int wave = tid >> 6, lane = tid & 63;
  const int wm = (wave & 1) * WMT, wn = (wave >> 1) * WNT;
  const int m0 = blockIdx.x * BM, n0 = blockIdx.y * BN;
  const int lq = lane >> 4, lm = lane & 15;
  const int srow = tid >> 2;          // 0..63
  const int skk = (tid & 3) * 8;      // 0,8,16,24
  constexpr int PASS_A = BM / 64, PASS_B = BN / 64;

  f32x4 acc[MF][NF] = {};

  for (int k0 = 0; k0 < K; k0 += BK) {
    __syncthreads();
    #pragma unroll
    for (int ps = 0; ps < PASS_A; ++ps) {
      int r = srow + ps * 64;
      bf16x8 v = *(const bf16x8*)(A + (size_t)(m0 + r) * K + k0 + skk);
      *(bf16x8*)(sA + r * LDSK + skk) = v;
    }
    #pragma unroll
    for (int ps = 0; ps < PASS_B; ++ps) {
      int r = srow + ps * 64;
      bf16x8 v = *(const bf16x8*)(W + (size_t)(n0 + r) * K + k0 + skk);
      *(bf16x8*)(sB + r * LDSK + skk) = v;
    }
    __syncthreads();
    bf16x8 af[MF], bfr[NF];
    #pragma unroll
    for (int mi = 0; mi < MF; ++mi)
      af[mi] = *(const bf16x8*)(sA + (wm + mi * 16 + lm) * LDSK + lq * 8);
    #pragma unroll
    for (int ni = 0; ni < NF; ++ni)
      bfr[ni] = *(const bf16x8*)(sB + (wn + ni * 16 + lm) * LDSK + lq * 8);
    #pragma unroll
    for (int mi = 0; mi < MF; ++mi)
      #pragma unroll
      for (int ni = 0; ni < NF; ++ni)
        acc[mi][ni] = __builtin_amdgcn_mfma_f32_16x16x32_bf16(
            af[mi], bfr[ni], acc[mi][ni], 0, 0, 0);
  }

  #pragma unroll
  for (int mi = 0; mi < MF; ++mi) {
    #pragma unroll
    for (int ni = 0; ni < NF; ++ni) {
      int col = n0 + wn + ni * 16 + lm;
      float bv = bias ? bias[col] : 0.f;
      #pragma unroll
      for (int r2 = 0; r2 < 4; ++r2) {
        int row = m0 + wm + mi * 16 + lq * 4 + r2;
        float vv = acc[mi][ni][r2] + bv;
        if (OUT_BF16)
          ((unsigned short*)Cout)[(size_t)row * N + col] = f2bf(vv);
        else
          ((float*)Cout)[(size_t)row * N + col] = vv;
      }
    }
  }
}

// ---------------- softmax over last dim, one thread per row ----------------
__global__ void softmax_rows(float* __restrict__ x, int rows, int w) {
  int r = blockIdx.x * blockDim.x + threadIdx.x;
  if (r >= rows) return;
  float* p = x + (size_t)r * w;
  float mx = -1e30f;
  for (int i = 0; i < w; ++i) mx = fmaxf(mx, p[i]);
  float s = 0.f;
  for (int i = 0; i < w; ++i) { float e = __expf(p[i] - mx); p[i] = e; s += e; }
  float inv = 1.f / s;
  for (int i = 0; i < w; ++i) p[i] *= inv;
}

// ---------------- MS-deform bilinear sampling ------------------------------
// One wave per (n,q,h); lane = d (DH=64). 32x32 levels.
// value:(B, nLev*1024, 16, 64) bf16; off:(B,1024,16,nLev,4,2) f32;
// attw:(B,1024,16,nLev*4) f32; out:(B,1024,1024) bf16.
__global__ __launch_bounds__(256) void ms_sample_kernel(
    const unsigned short* __restrict__ value, const float* __restrict__ off,
    const float* __restrict__ attw, unsigned short* __restrict__ out, int nLev) {
  int gid = blockIdx.x * 4 + (threadIdx.x >> 6);
  int lane = threadIdx.x & 63;
  int h = gid & 15;
  int q = (gid >> 4) & 1023;
  int n = gid >> 14;
  float refx = ((q & 31) + 0.5f) * (1.f / 32.f);
  float refy = ((q >> 5) + 0.5f) * (1.f / 32.f);
  const float* offp = off + (size_t)gid * nLev * 8;
  const float* awp = attw + (size_t)gid * nLev * 4;
  float acc = 0.f;
  for (int l = 0; l < nLev; ++l) {
    const unsigned short* vl =
        value + ((size_t)(n * nLev + l) * 1024) * 1024 + h * 64 + lane;
    #pragma unroll
    for (int p = 0; p < 4; ++p) {
      float ox = offp[l * 8 + p * 2 + 0];
      float oy = offp[l * 8 + p * 2 + 1];
      float aw = awp[l * 4 + p];
      float xx = (refx + ox * (1.f / 32.f)) * 32.f - 0.5f;
      float yy = (refy + oy * (1.f / 32.f)) * 32.f - 0.5f;
      float x0 = floorf(xx), y0 = floorf(yy);
      float fx = xx - x0, fy = yy - y0;
      int ix = (int)x0, iy = (int)y0;
      float w00 = (1.f - fx) * (1.f - fy) * aw;
      float w01 = fx * (1.f - fy) * aw;
      float w10 = (1.f - fx) * fy * aw;
      float w11 = fx * fy * aw;
      if (iy >= 0 && iy < 32) {
        if (ix >= 0 && ix < 32)
          acc += w00 * bf2f(vl[(size_t)(iy * 32 + ix) * 1024]);
        if (ix + 1 >= 0 && ix + 1 < 32)
          acc += w01 * bf2f(vl[(size_t)(iy * 32 + ix + 1) * 1024]);
      }
      if (iy + 1 >= 0 && iy + 1 < 32) {
        if (ix >= 0 && ix < 32)
          acc += w10 * bf2f(vl[(size_t)((iy + 1) * 32 + ix) * 1024]);
        if (ix + 1 >= 0 && ix + 1 < 32)
          acc += w11 * bf2f(vl[(size_t)((iy + 1) * 32 + ix + 1) * 1024]);
      }
    }
  }
  out[(size_t)gid * 64 + lane] = f2bf(acc);
}

// ---------------- final: out = src3 + g1*(attn + g2*attn2) -----------------
__global__ void final_kernel(const float* __restrict__ src3,
                             const float* __restrict__ attn,
                             const float* __restrict__ attn2,
                             const float* __restrict__ g1,
                             const float* __restrict__ g2,
                             float* __restrict__ out) {
  int i = blockIdx.x * 256 + threadIdx.x;  // i indexes float4, 1M total
  float4 a = ((const float4*)attn)[i];
  float4 b = ((const float4*)attn2)[i];
  float4 s = ((const float4*)src3)[i];
  int d4 = i & 255;
  float4 G1 = ((const float4*)g1)[d4];
  float4 G2 = ((const float4*)g2)[d4];
  float4 o;
  o.x = s.x + G1.x * (a.x + G2.x * b.x);
  o.y = s.y + G1.y * (a.y + G2.y * b.y);
  o.z = s.z + G1.z * (a.z + G2.z * b.z);
  o.w = s.w + G1.w * (a.w + G2.w * b.w);
  ((float4*)out)[i] = o;
}

// ---------------------------------------------------------------------------
extern "C" void kernel_launch(void* const* d_in, const int* in_sizes, int n_in,
                              void* d_out, int out_size, void* d_ws,
                              size_t ws_size, hipStream_t stream) {
  (void)in_sizes; (void)n_in; (void)out_size; (void)ws_size;
  const float* src[4] = {(const float*)d_in[0], (const float*)d_in[1],
                         (const float*)d_in[2], (const float*)d_in[3]};
  const float* qn_g = (const float*)d_in[4];
  const float* qn_b = (const float*)d_in[5];
  const float* fn_g = (const float*)d_in[6];
  const float* fn_b = (const float*)d_in[7];
  const float* n1_g = (const float*)d_in[8];
  const float* n1_b = (const float*)d_in[9];
  const float* gamma1 = (const float*)d_in[10];
  const float* gamma2 = (const float*)d_in[11];
  const float* ca_vw = (const float*)d_in[12];
  const float* ca_vb = (const float*)d_in[13];
  const float* ca_ow = (const float*)d_in[14];
  const float* ca_ob = (const float*)d_in[15];
  const float* ca_aw = (const float*)d_in[16];
  const float* ca_ab = (const float*)d_in[17];
  const float* ca_pw = (const float*)d_in[18];
  const float* ca_pb = (const float*)d_in[19];
  const float* sa_vw = (const float*)d_in[20];
  const float* sa_vb = (const float*)d_in[21];
  const float* sa_ow = (const float*)d_in[22];
  const float* sa_ob = (const float*)d_in[23];
  const float* sa_aw = (const float*)d_in[24];
  const float* sa_ab = (const float*)d_in[25];
  const float* sa_pw = (const float*)d_in[26];
  const float* sa_pb = (const float*)d_in[27];

  // ---- workspace layout (all offsets 256B aligned) ----
  char* wsp = (char*)d_ws;
  size_t off = 0;
  auto alloc = [&](size_t bytes) {
    char* r = wsp + off;
    off = (off + bytes + 255) & ~(size_t)255;
    return r;
  };
  const size_t MB = 1024 * 1024;
  unsigned short* w_ca_vw = (unsigned short*)alloc(1024 * 1024 * 2);
  unsigned short* w_ca_ow = (unsigned short*)alloc(512 * 1024 * 2);
  unsigned short* w_ca_aw = (unsigned short*)alloc(256 * 1024 * 2);
  unsigned short* w_ca_pw = (unsigned short*)alloc(1024 * 1024 * 2);
  unsigned short* w_sa_vw = (unsigned short*)alloc(1024 * 1024 * 2);
  unsigned short* w_sa_ow = (unsigned short*)alloc(128 * 1024 * 2);
  unsigned short* w_sa_aw = (unsigned short*)alloc(64 * 1024 * 2);
  unsigned short* w_sa_pw = (unsigned short*)alloc(1024 * 1024 * 2);
  char* R1 = alloc(32 * MB);  // f_ln bf16 | later: attn f32(16MB)+attn1 bf16(8MB)+samp_sa bf16(8MB)
  char* R2 = alloc(32 * MB);  // val_ca bf16 | later: val_sa bf16(8MB)+attn2 f32(16MB)
  char* R3 = alloc(8 * MB);   // q_ln bf16 | later: samp_ca bf16
  char* R4 = alloc(8 * MB);   // off_ca f32 | later: off_sa f32(2MB)+attw_sa f32(1MB)
  char* R5 = alloc(4 * MB);   // attw_ca f32

  unsigned short* f_ln   = (unsigned short*)R1;
  float*          attn   = (float*)R1;
  unsigned short* attn1  = (unsigned short*)(R1 + 16 * MB);
  unsigned short* samp_sa= (unsigned short*)(R1 + 24 * MB);
  unsigned short* val_ca = (unsigned short*)R2;
  unsigned short* val_sa = (unsigned short*)R2;
  float*          attn2  = (float*)(R2 + 8 * MB);
  unsigned short* q_ln   = (unsigned short*)R3;
  unsigned short* samp_ca= (unsigned short*)R3;
  float*          off_ca = (float*)R4;
  float*          off_sa = (float*)R4;
  float*          attw_sa= (float*)(R4 + 4 * MB);
  float*          attw_ca= (float*)R5;

  // ---- 1. weight conversions ----
  auto cvt = [&](const float* s, unsigned short* d, int n) {
    int n4 = n / 4;
    f2bf_kernel<<<(n4 + 255) / 256, 256, 0, stream>>>(s, d, n4);
  };
  cvt(ca_vw, w_ca_vw, 1024 * 1024);
  cvt(ca_ow, w_ca_ow, 512 * 1024);
  cvt(ca_aw, w_ca_aw, 256 * 1024);
  cvt(ca_pw, w_ca_pw, 1024 * 1024);
  cvt(sa_vw, w_sa_vw, 1024 * 1024);
  cvt(sa_ow, w_sa_ow, 128 * 1024);
  cvt(sa_aw, w_sa_aw, 64 * 1024);
  cvt(sa_pw, w_sa_pw, 1024 * 1024);

  // ---- 2. LayerNorms (query + 4 feat levels) ----
  ln_bf16_kernel<<<4096, 256, 0, stream>>>(src[3], qn_g, qn_b, q_ln, 0, 1024);
  for (int l = 0; l < 4; ++l)
    ln_bf16_kernel<<<4096, 256, 0, stream>>>(src[l], fn_g, fn_b, f_ln,
                                             l * 1024, 4096);

  // ---- 3. CA GEMMs ----
  gemm_bf16<128, 128, true><<<dim3(128, 8), 256, 0, stream>>>(
      f_ln, w_ca_vw, ca_vb, val_ca, 16384, 1024, 1024);
  gemm_bf16<128, 128, false><<<dim3(32, 4), 256, 0, stream>>>(
      q_ln, w_ca_ow, ca_ob, off_ca, 4096, 512, 1024);
  gemm_bf16<128, 128, false><<<dim3(32, 2), 256, 0, stream>>>(
      q_ln, w_ca_aw, ca_ab, attw_ca, 4096, 256, 1024);
  softmax_rows<<<256, 256, 0, stream>>>(attw_ca, 65536, 16);

  // ---- 4. CA sampling + projection ----
  ms_sample_kernel<<<16384, 256, 0, stream>>>(val_ca, off_ca, attw_ca,
                                              samp_ca, 4);
  gemm_bf16<128, 128, false><<<dim3(32, 8), 256, 0, stream>>>(
      samp_ca, w_ca_pw, ca_pb, attn, 4096, 1024, 1024);

  // ---- 5. SA branch ----
  ln_bf16_kernel<<<4096, 256, 0, stream>>>(attn, n1_g, n1_b, attn1, 0, 1024);
  gemm_bf16<128, 128, true><<<dim3(32, 8), 256, 0, stream>>>(
      attn1, w_sa_vw, sa_vb, val_sa, 4096, 1024, 1024);
  gemm_bf16<128, 128, false><<<dim3(32, 1), 256, 0, stream>>>(
      attn1, w_sa_ow, sa_ob, off_sa, 4096, 128, 1024);
  gemm_bf16<64, 64, false><<<dim3(64, 1), 256, 0, stream>>>(
      attn1, w_sa_aw, sa_ab, attw_sa, 4096, 64, 1024);
  softmax_rows<<<256, 256, 0, stream>>>(attw_sa, 65536, 4);
  ms_sample_kernel<<<16384, 256, 0, stream>>>(val_sa, off_sa, attw_sa,
                                              samp_sa, 1);
  gemm_bf16<128, 128, false><<<dim3(32, 8), 256, 0, stream>>>(
      samp_sa, w_sa_pw, sa_pb, attn2, 4096, 1024, 1024);

  // ---- 6. final combine ----
  final_kernel<<<4096, 256, 0, stream>>>(src[3], attn, attn2, gamma1, gamma2,
                                         (float*)d_out);
}

// Round 2
// 482.920 us; speedup vs baseline: 1.4257x; 1.4257x over previous
//
#include <hip/hip_runtime.h>

// ---------------------------------------------------------------------------
// MSCrossAttnBlock on MI355X (gfx950).
// B=4, E=32, LQ=1024, D=1024, NH=16, DH=64, NP=4. All levels are 32x32.
// R1: rewrote ms_sample (4 heads/wave, ushort4 gathers, branchless corners,
//     fused softmax); merged cvt kernels (8->1) and feat-LN kernels (4->1).
// ---------------------------------------------------------------------------

#define DEV __device__ __forceinline__

typedef float f32x4 __attribute__((ext_vector_type(4)));
typedef __bf16 bf16x8 __attribute__((ext_vector_type(8)));

DEV unsigned short f2bf(float f) {
  union { float f; unsigned u; } a; a.f = f;
  unsigned r = a.u + 0x7fffu + ((a.u >> 16) & 1u);
  return (unsigned short)(r >> 16);
}
DEV float bf2f(unsigned short h) {
  union { unsigned u; float f; } a; a.u = ((unsigned)h) << 16;
  return a.f;
}

// ---------------- merged weight fp32 -> bf16 conversion --------------------
// All 8 bf16 weight buffers are contiguous in ws; segments in float4 units.
struct CvtArgs {
  const float* src[8];
  unsigned short* dst;
  int off4[9];  // prefix sums, float4 units
};

__global__ __launch_bounds__(256) void f2bf_multi(CvtArgs a) {
  int i = blockIdx.x * 256 + threadIdx.x;  // float4 index, exact grid
  int seg = 0;
  #pragma unroll
  for (int s = 1; s < 8; ++s) seg += (i >= a.off4[s]) ? 1 : 0;
  const float4 v = ((const float4*)a.src[seg])[i - a.off4[seg]];
  unsigned short* o = a.dst + (size_t)i * 4;
  o[0] = f2bf(v.x); o[1] = f2bf(v.y); o[2] = f2bf(v.z); o[3] = f2bf(v.w);
}

// ---------------- LayerNorm body (D=1024), 256 thr per row -----------------
DEV void ln_row(const float* __restrict__ xr, const float* __restrict__ g,
                const float* __restrict__ b, unsigned short* __restrict__ op_row) {
  float4 v = ((const float4*)xr)[threadIdx.x];
  float s  = v.x + v.y + v.z + v.w;
  float s2 = v.x*v.x + v.y*v.y + v.z*v.z + v.w*v.w;
  #pragma unroll
  for (int o = 32; o; o >>= 1) { s += __shfl_down(s, o); s2 += __shfl_down(s2, o); }
  __shared__ float red[8];
  int wave = threadIdx.x >> 6, lane = threadIdx.x & 63;
  if (lane == 0) { red[wave] = s; red[4 + wave] = s2; }
  __syncthreads();
  if (threadIdx.x == 0) {
    float ts  = red[0] + red[1] + red[2] + red[3];
    float ts2 = red[4] + red[5] + red[6] + red[7];
    float mean = ts * (1.f / 1024.f);
    float var  = ts2 * (1.f / 1024.f) - mean * mean;
    red[0] = mean; red[1] = rsqrtf(var + 1e-6f);
  }
  __syncthreads();
  float mean = red[0], rstd = red[1];
  float4 gg = ((const float4*)g)[threadIdx.x];
  float4 bb = ((const float4*)b)[threadIdx.x];
  unsigned short* op = op_row + threadIdx.x * 4;
  op[0] = f2bf((v.x - mean) * rstd * gg.x + bb.x);
  op[1] = f2bf((v.y - mean) * rstd * gg.y + bb.y);
  op[2] = f2bf((v.z - mean) * rstd * gg.z + bb.z);
  op[3] = f2bf((v.w - mean) * rstd * gg.w + bb.w);
}

__global__ __launch_bounds__(256) void ln_bf16_kernel(
    const float* __restrict__ x, const float* __restrict__ g,
    const float* __restrict__ b, unsigned short* __restrict__ out) {
  int row = blockIdx.x;
  ln_row(x + (size_t)row * 1024, g, b, out + (size_t)row * 1024);
}

// 4 feat levels -> f_ln (B,4,1024,1024) batch-major (levels inner)
__global__ __launch_bounds__(256) void ln4_kernel(
    const float* __restrict__ s0, const float* __restrict__ s1,
    const float* __restrict__ s2, const float* __restrict__ s3,
    const float* __restrict__ g, const float* __restrict__ b,
    unsigned short* __restrict__ out) {
  int blk = blockIdx.x;            // 0..16383
  int l = blk >> 12, inner = blk & 4095;  // inner = batch*1024 + r
  const float* srcs[4] = {s0, s1, s2, s3};
  int orow = (inner >> 10) * 4096 + l * 1024 + (inner & 1023);
  ln_row(srcs[l] + (size_t)inner * 1024, g, b, out + (size_t)orow * 1024);
}

// ---------------- bf16 MFMA GEMM: C[M,N] = A[M,K] @ W[N,K]^T + bias --------
template <int BM, int BN, bool OUT_BF16>
__global__ __launch_bounds__(256) void gemm_bf16(
    const unsigned short* __restrict__ A, const unsigned short* __restrict__ W,
    const float* __restrict__ bias, void* __restrict__ Cout,
    int M, int N, int K) {
  constexpr int BK = 32;
  constexpr int WMT = BM / 2, WNT = BN / 2;
  constexpr int MF = WMT / 16, NF = WNT / 16;
  constexpr int LDSK = BK + 8;
  __shared__ __align__(16) unsigned short sA[BM * LDSK];
  __shared__ __align__(16) unsigned short sB[BN * LDSK];
  const int tid = threadIdx.x;
  const int wave = tid >> 6, lane = tid & 63;
  const int wm = (wave & 1) * WMT, wn = (wave >> 1) * WNT;
  const int m0 = blockIdx.x * BM, n0 = blockIdx.y * BN;
  const int lq = lane >> 4, lm = lane & 15;
  const int srow = tid >> 2;
  const int skk = (tid & 3) * 8;
  constexpr int PASS_A = BM / 64, PASS_B = BN / 64;

  f32x4 acc[MF][NF] = {};

  for (int k0 = 0; k0 < K; k0 += BK) {
    __syncthreads();
    #pragma unroll
    for (int ps = 0; ps < PASS_A; ++ps) {
      int r = srow + ps * 64;
      bf16x8 v = *(const bf16x8*)(A + (size_t)(m0 + r) * K + k0 + skk);
      *(bf16x8*)(sA + r * LDSK + skk) = v;
    }
    #pragma unroll
    for (int ps = 0; ps < PASS_B; ++ps) {
      int r = srow + ps * 64;
      bf16x8 v = *(const bf16x8*)(W + (size_t)(n0 + r) * K + k0 + skk);
      *(bf16x8*)(sB + r * LDSK + skk) = v;
    }
    __syncthreads();
    bf16x8 af[MF], bfr[NF];
    #pragma unroll
    for (int mi = 0; mi < MF; ++mi)
      af[mi] = *(const bf16x8*)(sA + (wm + mi * 16 + lm) * LDSK + lq * 8);
    #pragma unroll
    for (int ni = 0; ni < NF; ++ni)
      bfr[ni] = *(const bf16x8*)(sB + (wn + ni * 16 + lm) * LDSK + lq * 8);
    #pragma unroll
    for (int mi = 0; mi < MF; ++mi)
      #pragma unroll
      for (int ni = 0; ni < NF; ++ni)
        acc[mi][ni] = __builtin_amdgcn_mfma_f32_16x16x32_bf16(
            af[mi], bfr[ni], acc[mi][ni], 0, 0, 0);
  }

  #pragma unroll
  for (int mi = 0; mi < MF; ++mi) {
    #pragma unroll
    for (int ni = 0; ni < NF; ++ni) {
      int col = n0 + wn + ni * 16 + lm;
      float bv = bias ? bias[col] : 0.f;
      #pragma unroll
      for (int r2 = 0; r2 < 4; ++r2) {
        int row = m0 + wm + mi * 16 + lq * 4 + r2;
        float vv = acc[mi][ni][r2] + bv;
        if (OUT_BF16)
          ((unsigned short*)Cout)[(size_t)row * N + col] = f2bf(vv);
        else
          ((float*)Cout)[(size_t)row * N + col] = vv;
      }
    }
  }
}

// ---------------- fused softmax + MS-deform bilinear sampling --------------
// One block per (n,q); wave handles 4 heads; lane = (head_sub<<4)|(c/4).
// value:(B, NLEV*1024, 16, 64) bf16; off logits laid out as GEMM C rows:
//   off:(B*1024, 16*NLEV*8) f32, logits:(B*1024, 16*NLEV*4) f32 (raw scores).
// out:(B*1024, 16, 64) bf16.
template <int NLEV>
__global__ __launch_bounds__(256) void ms_sample_fused(
    const unsigned short* __restrict__ value, const float* __restrict__ off,
    const float* __restrict__ logits, unsigned short* __restrict__ out) {
  const int nq = blockIdx.x;               // n*1024 + q
  const int wave = threadIdx.x >> 6, lane = threadIdx.x & 63;
  const int h = (wave << 2) + (lane >> 4);
  const int c = (lane & 15) << 2;          // channel base (0..60)
  const int q = nq & 1023, n = nq >> 10;
  const float* offp = off + ((size_t)nq * 16 + h) * (NLEV * 8);
  const float* lgp  = logits + ((size_t)nq * 16 + h) * (NLEV * 4);

  // softmax over NLEV*4 (redundant across the 16 lanes of a head group)
  float lg[NLEV * 4];
  #pragma unroll
  for (int i = 0; i < NLEV; ++i) {
    float4 v = ((const float4*)lgp)[i];
    lg[4*i] = v.x; lg[4*i+1] = v.y; lg[4*i+2] = v.z; lg[4*i+3] = v.w;
  }
  float mx = lg[0];
  #pragma unroll
  for (int i = 1; i < NLEV * 4; ++i) mx = fmaxf(mx, lg[i]);
  float ssum = 0.f;
  #pragma unroll
  for (int i = 0; i < NLEV * 4; ++i) { lg[i] = __expf(lg[i] - mx); ssum += lg[i]; }
  const float inv = 1.f / ssum;

  const float fqx = (float)(q & 31), fqy = (float)(q >> 5);
  float a0 = 0.f, a1 = 0.f, a2 = 0.f, a3 = 0.f;

  #pragma unroll
  for (int l = 0; l < NLEV; ++l) {
    const unsigned short* vl =
        value + ((size_t)(n * NLEV + l) << 20) + h * 64 + c;
    #pragma unroll
    for (int p = 0; p < 4; ++p) {
      float2 o2 = ((const float2*)offp)[l * 4 + p];
      float aw = lg[l * 4 + p] * inv;
      // x = (refx + ox/32)*32 - 0.5 = (q&31) + ox ; same for y
      float xx = fqx + o2.x, yy = fqy + o2.y;
      float xf = floorf(xx), yf = floorf(yy);
      float fx = xx - xf, fy = yy - yf;
      int ix = (int)xf, iy = (int)yf;
      int ix1 = ix + 1, iy1 = iy + 1;
      float vx0 = ((unsigned)ix  < 32u) ? 1.f : 0.f;
      float vx1 = ((unsigned)ix1 < 32u) ? 1.f : 0.f;
      float vy0 = ((unsigned)iy  < 32u) ? 1.f : 0.f;
      float vy1 = ((unsigned)iy1 < 32u) ? 1.f : 0.f;
      int cx0 = min(max(ix, 0), 31), cx1 = min(max(ix1, 0), 31);
      int cy0 = min(max(iy, 0), 31), cy1 = min(max(iy1, 0), 31);
      float w00 = (1.f - fx) * (1.f - fy) * vx0 * vy0 * aw;
      float w01 = fx * (1.f - fy) * vx1 * vy0 * aw;
      float w10 = (1.f - fx) * fy * vx0 * vy1 * aw;
      float w11 = fx * fy * vx1 * vy1 * aw;
      ushort4 u00 = *(const ushort4*)(vl + ((size_t)(cy0 * 32 + cx0) << 10));
      ushort4 u01 = *(const ushort4*)(vl + ((size_t)(cy0 * 32 + cx1) << 10));
      ushort4 u10 = *(const ushort4*)(vl + ((size_t)(cy1 * 32 + cx0) << 10));
      ushort4 u11 = *(const ushort4*)(vl + ((size_t)(cy1 * 32 + cx1) << 10));
      a0 += w00 * bf2f(u00.x) + w01 * bf2f(u01.x) + w10 * bf2f(u10.x) + w11 * bf2f(u11.x);
      a1 += w00 * bf2f(u00.y) + w01 * bf2f(u01.y) + w10 * bf2f(u10.y) + w11 * bf2f(u11.y);
      a2 += w00 * bf2f(u00.z) + w01 * bf2f(u01.z) + w10 * bf2f(u10.z) + w11 * bf2f(u11.z);
      a3 += w00 * bf2f(u00.w) + w01 * bf2f(u01.w) + w10 * bf2f(u10.w) + w11 * bf2f(u11.w);
    }
  }
  ushort4 r;
  r.x = f2bf(a0); r.y = f2bf(a1); r.z = f2bf(a2); r.w = f2bf(a3);
  *(ushort4*)(out + ((size_t)nq * 16 + h) * 64 + c) = r;
}

// ---------------- final: out = src3 + g1*(attn + g2*attn2) -----------------
__global__ __launch_bounds__(256) void final_kernel(
    const float* __restrict__ src3, const float* __restrict__ attn,
    const float* __restrict__ attn2, const float* __restrict__ g1,
    const float* __restrict__ g2, float* __restrict__ out) {
  int i = blockIdx.x * 256 + threadIdx.x;  // float4 index, 1M total
  float4 a = ((const float4*)attn)[i];
  float4 b = ((const float4*)attn2)[i];
  float4 s = ((const float4*)src3)[i];
  int d4 = i & 255;
  float4 G1 = ((const float4*)g1)[d4];
  float4 G2 = ((const float4*)g2)[d4];
  float4 o;
  o.x = s.x + G1.x * (a.x + G2.x * b.x);
  o.y = s.y + G1.y * (a.y + G2.y * b.y);
  o.z = s.z + G1.z * (a.z + G2.z * b.z);
  o.w = s.w + G1.w * (a.w + G2.w * b.w);
  ((float4*)out)[i] = o;
}

// ---------------------------------------------------------------------------
extern "C" void kernel_launch(void* const* d_in, const int* in_sizes, int n_in,
                              void* d_out, int out_size, void* d_ws,
                              size_t ws_size, hipStream_t stream) {
  (void)in_sizes; (void)n_in; (void)out_size; (void)ws_size;
  const float* src[4] = {(const float*)d_in[0], (const float*)d_in[1],
                         (const float*)d_in[2], (const float*)d_in[3]};
  const float* qn_g = (const float*)d_in[4];
  const float* qn_b = (const float*)d_in[5];
  const float* fn_g = (const float*)d_in[6];
  const float* fn_b = (const float*)d_in[7];
  const float* n1_g = (const float*)d_in[8];
  const float* n1_b = (const float*)d_in[9];
  const float* gamma1 = (const float*)d_in[10];
  const float* gamma2 = (const float*)d_in[11];
  const float* ca_vw = (const float*)d_in[12];
  const float* ca_vb = (const float*)d_in[13];
  const float* ca_ow = (const float*)d_in[14];
  const float* ca_ob = (const float*)d_in[15];
  const float* ca_aw = (const float*)d_in[16];
  const float* ca_ab = (const float*)d_in[17];
  const float* ca_pw = (const float*)d_in[18];
  const float* ca_pb = (const float*)d_in[19];
  const float* sa_vw = (const float*)d_in[20];
  const float* sa_vb = (const float*)d_in[21];
  const float* sa_ow = (const float*)d_in[22];
  const float* sa_ob = (const float*)d_in[23];
  const float* sa_aw = (const float*)d_in[24];
  const float* sa_ab = (const float*)d_in[25];
  const float* sa_pw = (const float*)d_in[26];
  const float* sa_pb = (const float*)d_in[27];

  // ---- workspace layout ----
  char* wsp = (char*)d_ws;
  size_t off = 0;
  auto alloc = [&](size_t bytes) {
    char* r = wsp + off;
    off = (off + bytes + 255) & ~(size_t)255;
    return r;
  };
  const size_t MB = 1024 * 1024;
  // 8 bf16 weight buffers — contiguous (every size is a 256B multiple)
  unsigned short* w_ca_vw = (unsigned short*)alloc(1024 * 1024 * 2);
  unsigned short* w_ca_ow = (unsigned short*)alloc(512 * 1024 * 2);
  unsigned short* w_ca_aw = (unsigned short*)alloc(256 * 1024 * 2);
  unsigned short* w_ca_pw = (unsigned short*)alloc(1024 * 1024 * 2);
  unsigned short* w_sa_vw = (unsigned short*)alloc(1024 * 1024 * 2);
  unsigned short* w_sa_ow = (unsigned short*)alloc(128 * 1024 * 2);
  unsigned short* w_sa_aw = (unsigned short*)alloc(64 * 1024 * 2);
  unsigned short* w_sa_pw = (unsigned short*)alloc(1024 * 1024 * 2);
  char* R1 = alloc(32 * MB);  // f_ln bf16 | attn f32 + attn1 bf16 + samp_sa bf16
  char* R2 = alloc(32 * MB);  // val_ca bf16 | val_sa bf16 + attn2 f32
  char* R3 = alloc(8 * MB);   // q_ln bf16 | samp_ca bf16
  char* R4 = alloc(8 * MB);   // off_ca f32 | off_sa f32 + attw_sa f32
  char* R5 = alloc(4 * MB);   // attw_ca f32 (raw logits; softmax fused)

  unsigned short* f_ln    = (unsigned short*)R1;
  float*          attn    = (float*)R1;
  unsigned short* attn1   = (unsigned short*)(R1 + 16 * MB);
  unsigned short* samp_sa = (unsigned short*)(R1 + 24 * MB);
  unsigned short* val_ca  = (unsigned short*)R2;
  unsigned short* val_sa  = (unsigned short*)R2;
  float*          attn2   = (float*)(R2 + 8 * MB);
  unsigned short* q_ln    = (unsigned short*)R3;
  unsigned short* samp_ca = (unsigned short*)R3;
  float*          off_ca  = (float*)R4;
  float*          off_sa  = (float*)R4;
  float*          attw_sa = (float*)(R4 + 4 * MB);
  float*          attw_ca = (float*)R5;

  // ---- 1. merged weight conversion (one launch) ----
  CvtArgs ca;
  ca.src[0] = ca_vw; ca.src[1] = ca_ow; ca.src[2] = ca_aw; ca.src[3] = ca_pw;
  ca.src[4] = sa_vw; ca.src[5] = sa_ow; ca.src[6] = sa_aw; ca.src[7] = sa_pw;
  ca.dst = w_ca_vw;
  const int sizes4[8] = {262144, 131072, 65536, 262144, 262144, 32768, 16384, 262144};
  ca.off4[0] = 0;
  for (int i = 0; i < 8; ++i) ca.off4[i + 1] = ca.off4[i] + sizes4[i];
  f2bf_multi<<<ca.off4[8] / 256, 256, 0, stream>>>(ca);  // 5056 blocks

  // ---- 2. LayerNorms ----
  ln_bf16_kernel<<<4096, 256, 0, stream>>>(src[3], qn_g, qn_b, q_ln);
  ln4_kernel<<<16384, 256, 0, stream>>>(src[0], src[1], src[2], src[3],
                                        fn_g, fn_b, f_ln);

  // ---- 3. CA GEMMs ----
  gemm_bf16<128, 128, true><<<dim3(128, 8), 256, 0, stream>>>(
      f_ln, w_ca_vw, ca_vb, val_ca, 16384, 1024, 1024);
  gemm_bf16<128, 128, false><<<dim3(32, 4), 256, 0, stream>>>(
      q_ln, w_ca_ow, ca_ob, off_ca, 4096, 512, 1024);
  gemm_bf16<128, 128, false><<<dim3(32, 2), 256, 0, stream>>>(
      q_ln, w_ca_aw, ca_ab, attw_ca, 4096, 256, 1024);

  // ---- 4. CA sampling (softmax fused) + projection ----
  ms_sample_fused<4><<<4096, 256, 0, stream>>>(val_ca, off_ca, attw_ca, samp_ca);
  gemm_bf16<128, 128, false><<<dim3(32, 8), 256, 0, stream>>>(
      samp_ca, w_ca_pw, ca_pb, attn, 4096, 1024, 1024);

  // ---- 5. SA branch ----
  ln_bf16_kernel<<<4096, 256, 0, stream>>>(attn, n1_g, n1_b, attn1);
  gemm_bf16<128, 128, true><<<dim3(32, 8), 256, 0, stream>>>(
      attn1, w_sa_vw, sa_vb, val_sa, 4096, 1024, 1024);
  gemm_bf16<128, 128, false><<<dim3(32, 1), 256, 0, stream>>>(
      attn1, w_sa_ow, sa_ob, off_sa, 4096, 128, 1024);
  gemm_bf16<64, 64, false><<<dim3(64, 1), 256, 0, stream>>>(
      attn1, w_sa_aw, sa_ab, attw_sa, 4096, 64, 1024);
  ms_sample_fused<1><<<4096, 256, 0, stream>>>(val_sa, off_sa, attw_sa, samp_sa);
  gemm_bf16<128, 128, false><<<dim3(32, 8), 256, 0, stream>>>(
      samp_sa, w_sa_pw, sa_pb, attn2, 4096, 1024, 1024);

  // ---- 6. final combine ----
  final_kernel<<<4096, 256, 0, stream>>>(src[3], attn, attn2, gamma1, gamma2,
                                         (float*)d_out);
}

// Round 3
// 415.467 us; speedup vs baseline: 1.6571x; 1.1624x over previous
//
#include <hip/hip_runtime.h>

// ---------------------------------------------------------------------------
// MSCrossAttnBlock on MI355X (gfx950).
// B=4, E=32, LQ=1024, D=1024, NH=16, DH=64, NP=4. All levels are 32x32.
// R2: GEMM restaged via global_load_lds(16B) + XOR bank swizzle; fused GEMM
//     chains (CA off+attw N=768; SA val+off+attw N=1216); final combine fused
//     into proj_sa epilogue. 11 dispatches.
// ---------------------------------------------------------------------------

#define DEV __device__ __forceinline__

typedef float f32x4 __attribute__((ext_vector_type(4)));
typedef __bf16 bf16x8 __attribute__((ext_vector_type(8)));

DEV unsigned short f2bf(float f) {
  union { float f; unsigned u; } a; a.f = f;
  unsigned r = a.u + 0x7fffu + ((a.u >> 16) & 1u);
  return (unsigned short)(r >> 16);
}
DEV float bf2f(unsigned short h) {
  union { unsigned u; float f; } a; a.u = ((unsigned)h) << 16;
  return a.f;
}

// async global->LDS, 16B per lane; LDS dest = wave-uniform base + lane*16
DEV void gld16(const unsigned short* g, unsigned short* l) {
  __builtin_amdgcn_global_load_lds(
      (const __attribute__((address_space(1))) void*)g,
      (__attribute__((address_space(3))) void*)l, 16, 0, 0);
}

// ---------------- merged weight fp32 -> bf16 conversion --------------------
struct CvtArgs {
  const float* src[8];
  unsigned short* dst;
  int off4[9];  // prefix sums, float4 units
};

__global__ __launch_bounds__(256) void f2bf_multi(CvtArgs a) {
  int i = blockIdx.x * 256 + threadIdx.x;  // float4 index, exact grid
  int seg = 0;
  #pragma unroll
  for (int s = 1; s < 8; ++s) seg += (i >= a.off4[s]) ? 1 : 0;
  const float4 v = ((const float4*)a.src[seg])[i - a.off4[seg]];
  unsigned short* o = a.dst + (size_t)i * 4;
  o[0] = f2bf(v.x); o[1] = f2bf(v.y); o[2] = f2bf(v.z); o[3] = f2bf(v.w);
}

// ---------------- LayerNorm body (D=1024), 256 thr per row -----------------
DEV void ln_row(const float* __restrict__ xr, const float* __restrict__ g,
                const float* __restrict__ b, unsigned short* __restrict__ op_row) {
  float4 v = ((const float4*)xr)[threadIdx.x];
  float s  = v.x + v.y + v.z + v.w;
  float s2 = v.x*v.x + v.y*v.y + v.z*v.z + v.w*v.w;
  #pragma unroll
  for (int o = 32; o; o >>= 1) { s += __shfl_down(s, o); s2 += __shfl_down(s2, o); }
  __shared__ float red[8];
  int wave = threadIdx.x >> 6, lane = threadIdx.x & 63;
  if (lane == 0) { red[wave] = s; red[4 + wave] = s2; }
  __syncthreads();
  if (threadIdx.x == 0) {
    float ts  = red[0] + red[1] + red[2] + red[3];
    float ts2 = red[4] + red[5] + red[6] + red[7];
    float mean = ts * (1.f / 1024.f);
    float var  = ts2 * (1.f / 1024.f) - mean * mean;
    red[0] = mean; red[1] = rsqrtf(var + 1e-6f);
  }
  __syncthreads();
  float mean = red[0], rstd = red[1];
  float4 gg = ((const float4*)g)[threadIdx.x];
  float4 bb = ((const float4*)b)[threadIdx.x];
  unsigned short* op = op_row + threadIdx.x * 4;
  op[0] = f2bf((v.x - mean) * rstd * gg.x + bb.x);
  op[1] = f2bf((v.y - mean) * rstd * gg.y + bb.y);
  op[2] = f2bf((v.z - mean) * rstd * gg.z + bb.z);
  op[3] = f2bf((v.w - mean) * rstd * gg.w + bb.w);
}

__global__ __launch_bounds__(256) void ln_bf16_kernel(
    const float* __restrict__ x, const float* __restrict__ g,
    const float* __restrict__ b, unsigned short* __restrict__ out) {
  int row = blockIdx.x;
  ln_row(x + (size_t)row * 1024, g, b, out + (size_t)row * 1024);
}

// 4 feat levels -> f_ln (B,4,1024,1024) batch-major (levels inner)
__global__ __launch_bounds__(256) void ln4_kernel(
    const float* __restrict__ s0, const float* __restrict__ s1,
    const float* __restrict__ s2, const float* __restrict__ s3,
    const float* __restrict__ g, const float* __restrict__ b,
    unsigned short* __restrict__ out) {
  int blk = blockIdx.x;                   // 0..16383
  int l = blk >> 12, inner = blk & 4095;  // inner = batch*1024 + r
  const float* srcs[4] = {s0, s1, s2, s3};
  int orow = (inner >> 10) * 4096 + l * 1024 + (inner & 1023);
  ln_row(srcs[l] + (size_t)inner * 1024, g, b, out + (size_t)orow * 1024);
}

// ---------------- bf16 MFMA GEMM with global_load_lds staging --------------
// C[M,N] = A[M,K] @ W[N,K]^T (+bias in epilogue). BK=32.
// LDS layout: per 16-row granule (1 KB), slot l<-lane l = (r16*4 + cst)*16B,
// holding global k-chunk csrc = cst ^ ((r16>>1)&3)  (XOR bank swizzle).
// EPI: 0=f32, 1=bf16, 2=CA split(off512|attw256), 3=SA split(val1024 bf16|
//      off128 f32|attw64 f32), 4=final combine -> d_out.
struct GemmP {
  const unsigned short* A; const unsigned short* W;
  void* C; void* C1; void* C2;
  const float* b0; const float* b1; const float* b2;
  const float* src3; const float* g1; const float* g2; const float* attnp;
  int M, N, K;  // N = weight rows (logical out cols incl. guard bound)
};

template <int BM, int BN, int EPI>
__global__ __launch_bounds__(256) void gemm_glds(GemmP P) {
  constexpr int BK = 32;
  constexpr int WMT = BM / 2, WNT = BN / 2;
  constexpr int MF = WMT / 16, NF = WNT / 16;
  constexpr int AG = BM / 16, BG = BN / 16;   // 1KB granules
  constexpr int PA = AG / 4, PB = BG / 4;     // passes per wave
  __shared__ __align__(16) unsigned short sA[BM * BK];
  __shared__ __align__(16) unsigned short sB[BN * BK];
  const int tid = threadIdx.x;
  const int wave = tid >> 6, lane = tid & 63;
  const int wm = (wave & 1) * WMT, wn = (wave >> 1) * WNT;
  const int m0 = blockIdx.x * BM, n0 = blockIdx.y * BN;
  const int lq = lane >> 4, lm = lane & 15;
  // staging lane decomposition
  const int r16 = lane >> 2;
  const int cst = lane & 3;
  const int csrc = cst ^ ((r16 >> 1) & 3);
  // fragment read slot (swizzled)
  const int aslot = lq ^ ((lm >> 1) & 3);

  f32x4 acc[MF][NF] = {};

  for (int k0 = 0; k0 < P.K; k0 += BK) {
    __syncthreads();
    #pragma unroll
    for (int p = 0; p < PA; ++p) {
      int g = wave + 4 * p;
      int grow = m0 + g * 16 + r16;  // M is a multiple of BM for all callers
      gld16(P.A + (size_t)grow * P.K + k0 + csrc * 8, sA + g * 512);
    }
    #pragma unroll
    for (int p = 0; p < PB; ++p) {
      int g = wave + 4 * p;
      int grow = n0 + g * 16 + r16;
      grow = min(grow, P.N - 1);     // clamp for non-multiple N (SA: 1216)
      gld16(P.W + (size_t)grow * P.K + k0 + csrc * 8, sB + g * 512);
    }
    __syncthreads();  // drains vmcnt before any lane reads LDS
    bf16x8 af[MF], bfr[NF];
    #pragma unroll
    for (int mi = 0; mi < MF; ++mi)
      af[mi] = *(const bf16x8*)(sA + ((wm >> 4) + mi) * 512 + lm * 32 + aslot * 8);
    #pragma unroll
    for (int ni = 0; ni < NF; ++ni)
      bfr[ni] = *(const bf16x8*)(sB + ((wn >> 4) + ni) * 512 + lm * 32 + aslot * 8);
    #pragma unroll
    for (int mi = 0; mi < MF; ++mi)
      #pragma unroll
      for (int ni = 0; ni < NF; ++ni)
        acc[mi][ni] = __builtin_amdgcn_mfma_f32_16x16x32_bf16(
            af[mi], bfr[ni], acc[mi][ni], 0, 0, 0);
  }

  #pragma unroll
  for (int mi = 0; mi < MF; ++mi) {
    #pragma unroll
    for (int ni = 0; ni < NF; ++ni) {
      const int col = n0 + wn + ni * 16 + lm;
      #pragma unroll
      for (int r2 = 0; r2 < 4; ++r2) {
        const int row = m0 + wm + mi * 16 + lq * 4 + r2;
        float v = acc[mi][ni][r2];
        if constexpr (EPI == 0) {
          ((float*)P.C)[(size_t)row * 1024 + col] = v + P.b0[col];
        } else if constexpr (EPI == 1) {
          ((unsigned short*)P.C)[(size_t)row * 1024 + col] = f2bf(v + P.b0[col]);
        } else if constexpr (EPI == 2) {
          if (col < 512)
            ((float*)P.C)[(size_t)row * 512 + col] = v + P.b0[col];
          else
            ((float*)P.C1)[(size_t)row * 256 + col - 512] = v + P.b1[col - 512];
        } else if constexpr (EPI == 3) {
          if (col < 1024)
            ((unsigned short*)P.C)[(size_t)row * 1024 + col] = f2bf(v + P.b0[col]);
          else if (col < 1152)
            ((float*)P.C1)[(size_t)row * 128 + col - 1024] = v + P.b1[col - 1024];
          else if (col < 1216)
            ((float*)P.C2)[(size_t)row * 64 + col - 1152] = v + P.b2[col - 1152];
        } else {  // EPI == 4: out = src3 + g1*(attn + g2*(v+b))
          size_t i = (size_t)row * 1024 + col;
          float vv = v + P.b0[col];
          ((float*)P.C)[i] = P.src3[i] + P.g1[col] * (P.attnp[i] + P.g2[col] * vv);
        }
      }
    }
  }
}

// ---------------- fused softmax + MS-deform bilinear sampling --------------
template <int NLEV>
__global__ __launch_bounds__(256) void ms_sample_fused(
    const unsigned short* __restrict__ value, const float* __restrict__ off,
    const float* __restrict__ logits, unsigned short* __restrict__ out) {
  const int nq = blockIdx.x;               // n*1024 + q
  const int wave = threadIdx.x >> 6, lane = threadIdx.x & 63;
  const int h = (wave << 2) + (lane >> 4);
  const int c = (lane & 15) << 2;          // channel base (0..60)
  const int q = nq & 1023, n = nq >> 10;
  const float* offp = off + ((size_t)nq * 16 + h) * (NLEV * 8);
  const float* lgp  = logits + ((size_t)nq * 16 + h) * (NLEV * 4);

  float lg[NLEV * 4];
  #pragma unroll
  for (int i = 0; i < NLEV; ++i) {
    float4 v = ((const float4*)lgp)[i];
    lg[4*i] = v.x; lg[4*i+1] = v.y; lg[4*i+2] = v.z; lg[4*i+3] = v.w;
  }
  float mx = lg[0];
  #pragma unroll
  for (int i = 1; i < NLEV * 4; ++i) mx = fmaxf(mx, lg[i]);
  float ssum = 0.f;
  #pragma unroll
  for (int i = 0; i < NLEV * 4; ++i) { lg[i] = __expf(lg[i] - mx); ssum += lg[i]; }
  const float inv = 1.f / ssum;

  const float fqx = (float)(q & 31), fqy = (float)(q >> 5);
  float a0 = 0.f, a1 = 0.f, a2 = 0.f, a3 = 0.f;

  #pragma unroll
  for (int l = 0; l < NLEV; ++l) {
    const unsigned short* vl =
        value + ((size_t)(n * NLEV + l) << 20) + h * 64 + c;
    #pragma unroll
    for (int p = 0; p < 4; ++p) {
      float2 o2 = ((const float2*)offp)[l * 4 + p];
      float aw = lg[l * 4 + p] * inv;
      float xx = fqx + o2.x, yy = fqy + o2.y;
      float xf = floorf(xx), yf = floorf(yy);
      float fx = xx - xf, fy = yy - yf;
      int ix = (int)xf, iy = (int)yf;
      int ix1 = ix + 1, iy1 = iy + 1;
      float vx0 = ((unsigned)ix  < 32u) ? 1.f : 0.f;
      float vx1 = ((unsigned)ix1 < 32u) ? 1.f : 0.f;
      float vy0 = ((unsigned)iy  < 32u) ? 1.f : 0.f;
      float vy1 = ((unsigned)iy1 < 32u) ? 1.f : 0.f;
      int cx0 = min(max(ix, 0), 31), cx1 = min(max(ix1, 0), 31);
      int cy0 = min(max(iy, 0), 31), cy1 = min(max(iy1, 0), 31);
      float w00 = (1.f - fx) * (1.f - fy) * vx0 * vy0 * aw;
      float w01 = fx * (1.f - fy) * vx1 * vy0 * aw;
      float w10 = (1.f - fx) * fy * vx0 * vy1 * aw;
      float w11 = fx * fy * vx1 * vy1 * aw;
      ushort4 u00 = *(const ushort4*)(vl + ((size_t)(cy0 * 32 + cx0) << 10));
      ushort4 u01 = *(const ushort4*)(vl + ((size_t)(cy0 * 32 + cx1) << 10));
      ushort4 u10 = *(const ushort4*)(vl + ((size_t)(cy1 * 32 + cx0) << 10));
      ushort4 u11 = *(const ushort4*)(vl + ((size_t)(cy1 * 32 + cx1) << 10));
      a0 += w00 * bf2f(u00.x) + w01 * bf2f(u01.x) + w10 * bf2f(u10.x) + w11 * bf2f(u11.x);
      a1 += w00 * bf2f(u00.y) + w01 * bf2f(u01.y) + w10 * bf2f(u10.y) + w11 * bf2f(u11.y);
      a2 += w00 * bf2f(u00.z) + w01 * bf2f(u01.z) + w10 * bf2f(u10.z) + w11 * bf2f(u11.z);
      a3 += w00 * bf2f(u00.w) + w01 * bf2f(u01.w) + w10 * bf2f(u10.w) + w11 * bf2f(u11.w);
    }
  }
  ushort4 r;
  r.x = f2bf(a0); r.y = f2bf(a1); r.z = f2bf(a2); r.w = f2bf(a3);
  *(ushort4*)(out + ((size_t)nq * 16 + h) * 64 + c) = r;
}

// ---------------------------------------------------------------------------
extern "C" void kernel_launch(void* const* d_in, const int* in_sizes, int n_in,
                              void* d_out, int out_size, void* d_ws,
                              size_t ws_size, hipStream_t stream) {
  (void)in_sizes; (void)n_in; (void)out_size; (void)ws_size;
  const float* src[4] = {(const float*)d_in[0], (const float*)d_in[1],
                         (const float*)d_in[2], (const float*)d_in[3]};
  const float* qn_g = (const float*)d_in[4];
  const float* qn_b = (const float*)d_in[5];
  const float* fn_g = (const float*)d_in[6];
  const float* fn_b = (const float*)d_in[7];
  const float* n1_g = (const float*)d_in[8];
  const float* n1_b = (const float*)d_in[9];
  const float* gamma1 = (const float*)d_in[10];
  const float* gamma2 = (const float*)d_in[11];
  const float* ca_vw = (const float*)d_in[12];
  const float* ca_vb = (const float*)d_in[13];
  const float* ca_ow = (const float*)d_in[14];
  const float* ca_ob = (const float*)d_in[15];
  const float* ca_aw = (const float*)d_in[16];
  const float* ca_ab = (const float*)d_in[17];
  const float* ca_pw = (const float*)d_in[18];
  const float* ca_pb = (const float*)d_in[19];
  const float* sa_vw = (const float*)d_in[20];
  const float* sa_vb = (const float*)d_in[21];
  const float* sa_ow = (const float*)d_in[22];
  const float* sa_ob = (const float*)d_in[23];
  const float* sa_aw = (const float*)d_in[24];
  const float* sa_ab = (const float*)d_in[25];
  const float* sa_pw = (const float*)d_in[26];
  const float* sa_pb = (const float*)d_in[27];

  // ---- workspace layout ----
  char* wsp = (char*)d_ws;
  size_t off = 0;
  auto alloc = [&](size_t bytes) {
    char* r = wsp + off;
    off = (off + bytes + 255) & ~(size_t)255;
    return r;
  };
  const size_t MB = 1024 * 1024;
  // bf16 weights; ca_ow+ca_aw contiguous (N=768 fused GEMM);
  // sa_vw+sa_ow+sa_aw contiguous (N=1216 fused GEMM).
  unsigned short* w_ca_vw = (unsigned short*)alloc(1024 * 1024 * 2);
  unsigned short* w_ca_ow = (unsigned short*)alloc(512 * 1024 * 2);
  unsigned short* w_ca_aw = (unsigned short*)alloc(256 * 1024 * 2);
  unsigned short* w_ca_pw = (unsigned short*)alloc(1024 * 1024 * 2);
  unsigned short* w_sa_vw = (unsigned short*)alloc(1024 * 1024 * 2);
  unsigned short* w_sa_ow = (unsigned short*)alloc(128 * 1024 * 2);
  unsigned short* w_sa_aw = (unsigned short*)alloc(64 * 1024 * 2);
  unsigned short* w_sa_pw = (unsigned short*)alloc(1024 * 1024 * 2);
  (void)w_ca_aw; (void)w_sa_ow; (void)w_sa_aw;
  char* R1 = alloc(32 * MB);  // f_ln bf16 | attn f32 + attn1 bf16 + samp_sa bf16
  char* R2 = alloc(32 * MB);  // val_ca bf16 | val_sa bf16
  char* R3 = alloc(8 * MB);   // q_ln bf16 | samp_ca bf16
  char* R4 = alloc(8 * MB);   // off_ca f32 | off_sa f32 + attw_sa f32
  char* R5 = alloc(4 * MB);   // attw_ca f32 (raw logits; softmax fused)

  unsigned short* f_ln    = (unsigned short*)R1;
  float*          attn    = (float*)R1;
  unsigned short* attn1   = (unsigned short*)(R1 + 16 * MB);
  unsigned short* samp_sa = (unsigned short*)(R1 + 24 * MB);
  unsigned short* val_ca  = (unsigned short*)R2;
  unsigned short* val_sa  = (unsigned short*)R2;
  unsigned short* q_ln    = (unsigned short*)R3;
  unsigned short* samp_ca = (unsigned short*)R3;
  float*          off_ca  = (float*)R4;
  float*          off_sa  = (float*)R4;
  float*          attw_sa = (float*)(R4 + 4 * MB);
  float*          attw_ca = (float*)R5;

  // ---- 1. merged weight conversion ----
  CvtArgs ca;
  ca.src[0] = ca_vw; ca.src[1] = ca_ow; ca.src[2] = ca_aw; ca.src[3] = ca_pw;
  ca.src[4] = sa_vw; ca.src[5] = sa_ow; ca.src[6] = sa_aw; ca.src[7] = sa_pw;
  ca.dst = w_ca_vw;
  const int sizes4[8] = {262144, 131072, 65536, 262144, 262144, 32768, 16384, 262144};
  ca.off4[0] = 0;
  for (int i = 0; i < 8; ++i) ca.off4[i + 1] = ca.off4[i] + sizes4[i];
  f2bf_multi<<<ca.off4[8] / 256, 256, 0, stream>>>(ca);

  // ---- 2. LayerNorms ----
  ln_bf16_kernel<<<4096, 256, 0, stream>>>(src[3], qn_g, qn_b, q_ln);
  ln4_kernel<<<16384, 256, 0, stream>>>(src[0], src[1], src[2], src[3],
                                        fn_g, fn_b, f_ln);

  auto mkP = [](const unsigned short* A, const unsigned short* W, void* C,
                const float* b0, int M, int N, int K) {
    GemmP p{}; p.A = A; p.W = W; p.C = C; p.b0 = b0; p.M = M; p.N = N; p.K = K;
    return p;
  };

  // ---- 3. CA: value GEMM + fused off/attw GEMM ----
  gemm_glds<128, 128, 1><<<dim3(128, 8), 256, 0, stream>>>(
      mkP(f_ln, w_ca_vw, val_ca, ca_vb, 16384, 1024, 1024));
  {
    GemmP p = mkP(q_ln, w_ca_ow, off_ca, ca_ob, 4096, 768, 1024);
    p.C1 = attw_ca; p.b1 = ca_ab;
    gemm_glds<128, 128, 2><<<dim3(32, 6), 256, 0, stream>>>(p);
  }

  // ---- 4. CA sampling + projection ----
  ms_sample_fused<4><<<4096, 256, 0, stream>>>(val_ca, off_ca, attw_ca, samp_ca);
  gemm_glds<64, 128, 0><<<dim3(64, 8), 256, 0, stream>>>(
      mkP(samp_ca, w_ca_pw, attn, ca_pb, 4096, 1024, 1024));

  // ---- 5. SA branch ----
  ln_bf16_kernel<<<4096, 256, 0, stream>>>(attn, n1_g, n1_b, attn1);
  {
    GemmP p = mkP(attn1, w_sa_vw, val_sa, sa_vb, 4096, 1216, 1024);
    p.C1 = off_sa; p.b1 = sa_ob; p.C2 = attw_sa; p.b2 = sa_ab;
    gemm_glds<128, 128, 3><<<dim3(32, 10), 256, 0, stream>>>(p);
  }
  ms_sample_fused<1><<<4096, 256, 0, stream>>>(val_sa, off_sa, attw_sa, samp_sa);
  {
    GemmP p = mkP(samp_sa, w_sa_pw, d_out, sa_pb, 4096, 1024, 1024);
    p.src3 = src[3]; p.g1 = gamma1; p.g2 = gamma2; p.attnp = attn;
    gemm_glds<64, 128, 4><<<dim3(64, 8), 256, 0, stream>>>(p);
  }
}

// Round 4
// 366.646 us; speedup vs baseline: 1.8778x; 1.1332x over previous
//
#include <hip/hip_runtime.h>

// ---------------------------------------------------------------------------
// MSCrossAttnBlock on MI355X (gfx950).
// B=4, E=32, LQ=1024, D=1024, NH=16, DH=64, NP=4. All levels are 32x32.
// R3: GEMM = VGPR staging + XOR-swizzled conflict-free LDS (measured 0
//     conflicts in R2) + BK=64 (half the barriers) + 1D column-major tile
//     decode (same-A tiles share an XCD); BM=64 for M=4096 GEMMs; q-LN merged
//     into feat-LN. 10 dispatches.
// ---------------------------------------------------------------------------

#define DEV __device__ __forceinline__

typedef float f32x4 __attribute__((ext_vector_type(4)));
typedef __bf16 bf16x8 __attribute__((ext_vector_type(8)));

DEV unsigned short f2bf(float f) {
  union { float f; unsigned u; } a; a.f = f;
  unsigned r = a.u + 0x7fffu + ((a.u >> 16) & 1u);
  return (unsigned short)(r >> 16);
}
DEV float bf2f(unsigned short h) {
  union { unsigned u; float f; } a; a.u = ((unsigned)h) << 16;
  return a.f;
}

// ---------------- merged weight fp32 -> bf16 conversion --------------------
struct CvtArgs {
  const float* src[8];
  unsigned short* dst;
  int off4[9];  // prefix sums, float4 units
};

__global__ __launch_bounds__(256) void f2bf_multi(CvtArgs a) {
  int i = blockIdx.x * 256 + threadIdx.x;  // float4 index, exact grid
  int seg = 0;
  #pragma unroll
  for (int s = 1; s < 8; ++s) seg += (i >= a.off4[s]) ? 1 : 0;
  const float4 v = ((const float4*)a.src[seg])[i - a.off4[seg]];
  unsigned short* o = a.dst + (size_t)i * 4;
  o[0] = f2bf(v.x); o[1] = f2bf(v.y); o[2] = f2bf(v.z); o[3] = f2bf(v.w);
}

// ---------------- LayerNorm body (D=1024), 256 thr per row -----------------
DEV void ln_row(const float* __restrict__ xr, const float* __restrict__ g,
                const float* __restrict__ b, unsigned short* __restrict__ op_row) {
  float4 v = ((const float4*)xr)[threadIdx.x];
  float s  = v.x + v.y + v.z + v.w;
  float s2 = v.x*v.x + v.y*v.y + v.z*v.z + v.w*v.w;
  #pragma unroll
  for (int o = 32; o; o >>= 1) { s += __shfl_down(s, o); s2 += __shfl_down(s2, o); }
  __shared__ float red[8];
  int wave = threadIdx.x >> 6, lane = threadIdx.x & 63;
  if (lane == 0) { red[wave] = s; red[4 + wave] = s2; }
  __syncthreads();
  if (threadIdx.x == 0) {
    float ts  = red[0] + red[1] + red[2] + red[3];
    float ts2 = red[4] + red[5] + red[6] + red[7];
    float mean = ts * (1.f / 1024.f);
    float var  = ts2 * (1.f / 1024.f) - mean * mean;
    red[0] = mean; red[1] = rsqrtf(var + 1e-6f);
  }
  __syncthreads();
  float mean = red[0], rstd = red[1];
  float4 gg = ((const float4*)g)[threadIdx.x];
  float4 bb = ((const float4*)b)[threadIdx.x];
  unsigned short* op = op_row + threadIdx.x * 4;
  op[0] = f2bf((v.x - mean) * rstd * gg.x + bb.x);
  op[1] = f2bf((v.y - mean) * rstd * gg.y + bb.y);
  op[2] = f2bf((v.z - mean) * rstd * gg.z + bb.z);
  op[3] = f2bf((v.w - mean) * rstd * gg.w + bb.w);
}

__global__ __launch_bounds__(256) void ln_bf16_kernel(
    const float* __restrict__ x, const float* __restrict__ g,
    const float* __restrict__ b, unsigned short* __restrict__ out) {
  int row = blockIdx.x;
  ln_row(x + (size_t)row * 1024, g, b, out + (size_t)row * 1024);
}

// 4 feat levels -> f_ln (B,4,1024,1024), plus q_ln = LN(src3, qn) segment.
__global__ __launch_bounds__(256) void ln5_kernel(
    const float* __restrict__ s0, const float* __restrict__ s1,
    const float* __restrict__ s2, const float* __restrict__ s3,
    const float* __restrict__ fg, const float* __restrict__ fb,
    const float* __restrict__ qg, const float* __restrict__ qb,
    unsigned short* __restrict__ f_out, unsigned short* __restrict__ q_out) {
  int blk = blockIdx.x;                   // 0..20479
  int seg = blk >> 12, inner = blk & 4095;
  if (seg < 4) {
    const float* srcs[4] = {s0, s1, s2, s3};
    int orow = (inner >> 10) * 4096 + seg * 1024 + (inner & 1023);
    ln_row(srcs[seg] + (size_t)inner * 1024, fg, fb,
           f_out + (size_t)orow * 1024);
  } else {
    ln_row(s3 + (size_t)inner * 1024, qg, qb, q_out + (size_t)inner * 1024);
  }
}

// ---------------- bf16 MFMA GEMM, VGPR staging + swizzled LDS --------------
// C[M,N] = A[M,K] @ W[N,K]^T (+bias). BK=64 as two 32-k sub-tiles.
// LDS per sub-tile: 16-row granules of 512 shorts; slot (r16*4+cst)*8 shorts
// holds k-chunk csrc = cst ^ ((r16>>1)&3). Read slot: aslot = lq^((lm>>1)&3).
// (Layout measured conflict-free in R2: SQ_LDS_BANK_CONFLICT = 0.)
// EPI: 0=f32, 1=bf16, 2=CA split(off512|attw256), 3=SA split(val1024 bf16|
//      off128 f32|attw64 f32), 4=final combine -> d_out.
struct GemmP {
  const unsigned short* A; const unsigned short* W;
  void* C; void* C1; void* C2;
  const float* b0; const float* b1; const float* b2;
  const float* src3; const float* g1; const float* g2; const float* attnp;
  int M, N, K, tilesM;
};

template <int BM, int BN, int EPI>
__global__ __launch_bounds__(256) void gemm_v3(GemmP P) {
  constexpr int WMT = BM / 2, WNT = BN / 2;
  constexpr int MF = WMT / 16, NF = WNT / 16;
  constexpr int PA = BM / 64, PB = BN / 64;    // granule passes per sub-tile
  __shared__ __align__(16) unsigned short sA[BM * 64];
  __shared__ __align__(16) unsigned short sB[BN * 64];
  const int tid = threadIdx.x;
  const int wave = tid >> 6, lane = tid & 63;
  const int wm = (wave & 1) * WMT, wn = (wave >> 1) * WNT;
  const int id = blockIdx.x;
  const int m0 = (id % P.tilesM) * BM;
  const int n0 = (id / P.tilesM) * BN;
  const int lq = lane >> 4, lm = lane & 15;
  const int r16 = lane >> 2;                    // row within granule
  const int cst = lane & 3;                     // slot within row
  const int csrc = cst ^ ((r16 >> 1) & 3);      // global k-chunk for slot
  const int aslot = lq ^ ((lm >> 1) & 3);       // read slot for chunk lq

  f32x4 acc[MF][NF] = {};
  bf16x8 ald[2][PA], bld[2][PB];

  #pragma unroll 1
  for (int k0 = 0; k0 < P.K; k0 += 64) {
    // global -> VGPR (issued before the barrier; overlaps other waves)
    #pragma unroll
    for (int s = 0; s < 2; ++s) {
      #pragma unroll
      for (int p = 0; p < PA; ++p) {
        int grow = m0 + (wave + 4 * p) * 16 + r16;
        ald[s][p] = *(const bf16x8*)(P.A + (size_t)grow * P.K + k0 + s * 32 + csrc * 8);
      }
      #pragma unroll
      for (int p = 0; p < PB; ++p) {
        int grow = min(n0 + (wave + 4 * p) * 16 + r16, P.N - 1);
        bld[s][p] = *(const bf16x8*)(P.W + (size_t)grow * P.K + k0 + s * 32 + csrc * 8);
      }
    }
    __syncthreads();  // prev iteration's LDS reads complete
    #pragma unroll
    for (int s = 0; s < 2; ++s) {
      #pragma unroll
      for (int p = 0; p < PA; ++p)
        *(bf16x8*)(sA + s * BM * 32 + (wave + 4 * p) * 512 + (r16 * 4 + cst) * 8) = ald[s][p];
      #pragma unroll
      for (int p = 0; p < PB; ++p)
        *(bf16x8*)(sB + s * BN * 32 + (wave + 4 * p) * 512 + (r16 * 4 + cst) * 8) = bld[s][p];
    }
    __syncthreads();
    #pragma unroll
    for (int s = 0; s < 2; ++s) {
      bf16x8 af[MF], bfr[NF];
      #pragma unroll
      for (int mi = 0; mi < MF; ++mi)
        af[mi] = *(const bf16x8*)(sA + s * BM * 32 + ((wm >> 4) + mi) * 512 + lm * 32 + aslot * 8);
      #pragma unroll
      for (int ni = 0; ni < NF; ++ni)
        bfr[ni] = *(const bf16x8*)(sB + s * BN * 32 + ((wn >> 4) + ni) * 512 + lm * 32 + aslot * 8);
      #pragma unroll
      for (int mi = 0; mi < MF; ++mi)
        #pragma unroll
        for (int ni = 0; ni < NF; ++ni)
          acc[mi][ni] = __builtin_amdgcn_mfma_f32_16x16x32_bf16(
              af[mi], bfr[ni], acc[mi][ni], 0, 0, 0);
    }
  }

  #pragma unroll
  for (int mi = 0; mi < MF; ++mi) {
    #pragma unroll
    for (int ni = 0; ni < NF; ++ni) {
      const int col = n0 + wn + ni * 16 + lm;
      #pragma unroll
      for (int r2 = 0; r2 < 4; ++r2) {
        const int row = m0 + wm + mi * 16 + lq * 4 + r2;
        float v = acc[mi][ni][r2];
        if constexpr (EPI == 0) {
          ((float*)P.C)[(size_t)row * 1024 + col] = v + P.b0[col];
        } else if constexpr (EPI == 1) {
          ((unsigned short*)P.C)[(size_t)row * 1024 + col] = f2bf(v + P.b0[col]);
        } else if constexpr (EPI == 2) {
          if (col < 512)
            ((float*)P.C)[(size_t)row * 512 + col] = v + P.b0[col];
          else
            ((float*)P.C1)[(size_t)row * 256 + col - 512] = v + P.b1[col - 512];
        } else if constexpr (EPI == 3) {
          if (col < 1024)
            ((unsigned short*)P.C)[(size_t)row * 1024 + col] = f2bf(v + P.b0[col]);
          else if (col < 1152)
            ((float*)P.C1)[(size_t)row * 128 + col - 1024] = v + P.b1[col - 1024];
          else if (col < 1216)
            ((float*)P.C2)[(size_t)row * 64 + col - 1152] = v + P.b2[col - 1152];
        } else {  // EPI == 4: out = src3 + g1*(attn + g2*(v+b))
          size_t i = (size_t)row * 1024 + col;
          float vv = v + P.b0[col];
          ((float*)P.C)[i] = P.src3[i] + P.g1[col] * (P.attnp[i] + P.g2[col] * vv);
        }
      }
    }
  }
}

// ---------------- fused softmax + MS-deform bilinear sampling --------------
template <int NLEV>
__global__ __launch_bounds__(256) void ms_sample_fused(
    const unsigned short* __restrict__ value, const float* __restrict__ off,
    const float* __restrict__ logits, unsigned short* __restrict__ out) {
  const int nq = blockIdx.x;               // n*1024 + q
  const int wave = threadIdx.x >> 6, lane = threadIdx.x & 63;
  const int h = (wave << 2) + (lane >> 4);
  const int c = (lane & 15) << 2;          // channel base (0..60)
  const int q = nq & 1023, n = nq >> 10;
  const float* offp = off + ((size_t)nq * 16 + h) * (NLEV * 8);
  const float* lgp  = logits + ((size_t)nq * 16 + h) * (NLEV * 4);

  float lg[NLEV * 4];
  #pragma unroll
  for (int i = 0; i < NLEV; ++i) {
    float4 v = ((const float4*)lgp)[i];
    lg[4*i] = v.x; lg[4*i+1] = v.y; lg[4*i+2] = v.z; lg[4*i+3] = v.w;
  }
  float mx = lg[0];
  #pragma unroll
  for (int i = 1; i < NLEV * 4; ++i) mx = fmaxf(mx, lg[i]);
  float ssum = 0.f;
  #pragma unroll
  for (int i = 0; i < NLEV * 4; ++i) { lg[i] = __expf(lg[i] - mx); ssum += lg[i]; }
  const float inv = 1.f / ssum;

  const float fqx = (float)(q & 31), fqy = (float)(q >> 5);
  float a0 = 0.f, a1 = 0.f, a2 = 0.f, a3 = 0.f;

  #pragma unroll
  for (int l = 0; l < NLEV; ++l) {
    const unsigned short* vl =
        value + ((size_t)(n * NLEV + l) << 20) + h * 64 + c;
    #pragma unroll
    for (int p = 0; p < 4; ++p) {
      float2 o2 = ((const float2*)offp)[l * 4 + p];
      float aw = lg[l * 4 + p] * inv;
      float xx = fqx + o2.x, yy = fqy + o2.y;
      float xf = floorf(xx), yf = floorf(yy);
      float fx = xx - xf, fy = yy - yf;
      int ix = (int)xf, iy = (int)yf;
      int ix1 = ix + 1, iy1 = iy + 1;
      float vx0 = ((unsigned)ix  < 32u) ? 1.f : 0.f;
      float vx1 = ((unsigned)ix1 < 32u) ? 1.f : 0.f;
      float vy0 = ((unsigned)iy  < 32u) ? 1.f : 0.f;
      float vy1 = ((unsigned)iy1 < 32u) ? 1.f : 0.f;
      int cx0 = min(max(ix, 0), 31), cx1 = min(max(ix1, 0), 31);
      int cy0 = min(max(iy, 0), 31), cy1 = min(max(iy1, 0), 31);
      float w00 = (1.f - fx) * (1.f - fy) * vx0 * vy0 * aw;
      float w01 = fx * (1.f - fy) * vx1 * vy0 * aw;
      float w10 = (1.f - fx) * fy * vx0 * vy1 * aw;
      float w11 = fx * fy * vx1 * vy1 * aw;
      ushort4 u00 = *(const ushort4*)(vl + ((size_t)(cy0 * 32 + cx0) << 10));
      ushort4 u01 = *(const ushort4*)(vl + ((size_t)(cy0 * 32 + cx1) << 10));
      ushort4 u10 = *(const ushort4*)(vl + ((size_t)(cy1 * 32 + cx0) << 10));
      ushort4 u11 = *(const ushort4*)(vl + ((size_t)(cy1 * 32 + cx1) << 10));
      a0 += w00 * bf2f(u00.x) + w01 * bf2f(u01.x) + w10 * bf2f(u10.x) + w11 * bf2f(u11.x);
      a1 += w00 * bf2f(u00.y) + w01 * bf2f(u01.y) + w10 * bf2f(u10.y) + w11 * bf2f(u11.y);
      a2 += w00 * bf2f(u00.z) + w01 * bf2f(u01.z) + w10 * bf2f(u10.z) + w11 * bf2f(u11.z);
      a3 += w00 * bf2f(u00.w) + w01 * bf2f(u01.w) + w10 * bf2f(u10.w) + w11 * bf2f(u11.w);
    }
  }
  ushort4 r;
  r.x = f2bf(a0); r.y = f2bf(a1); r.z = f2bf(a2); r.w = f2bf(a3);
  *(ushort4*)(out + ((size_t)nq * 16 + h) * 64 + c) = r;
}

// ---------------------------------------------------------------------------
extern "C" void kernel_launch(void* const* d_in, const int* in_sizes, int n_in,
                              void* d_out, int out_size, void* d_ws,
                              size_t ws_size, hipStream_t stream) {
  (void)in_sizes; (void)n_in; (void)out_size; (void)ws_size;
  const float* src[4] = {(const float*)d_in[0], (const float*)d_in[1],
                         (const float*)d_in[2], (const float*)d_in[3]};
  const float* qn_g = (const float*)d_in[4];
  const float* qn_b = (const float*)d_in[5];
  const float* fn_g = (const float*)d_in[6];
  const float* fn_b = (const float*)d_in[7];
  const float* n1_g = (const float*)d_in[8];
  const float* n1_b = (const float*)d_in[9];
  const float* gamma1 = (const float*)d_in[10];
  const float* gamma2 = (const float*)d_in[11];
  const float* ca_vw = (const float*)d_in[12];
  const float* ca_vb = (const float*)d_in[13];
  const float* ca_ow = (const float*)d_in[14];
  const float* ca_ob = (const float*)d_in[15];
  const float* ca_aw = (const float*)d_in[16];
  const float* ca_ab = (const float*)d_in[17];
  const float* ca_pw = (const float*)d_in[18];
  const float* ca_pb = (const float*)d_in[19];
  const float* sa_vw = (const float*)d_in[20];
  const float* sa_vb = (const float*)d_in[21];
  const float* sa_ow = (const float*)d_in[22];
  const float* sa_ob = (const float*)d_in[23];
  const float* sa_aw = (const float*)d_in[24];
  const float* sa_ab = (const float*)d_in[25];
  const float* sa_pw = (const float*)d_in[26];
  const float* sa_pb = (const float*)d_in[27];

  // ---- workspace layout ----
  char* wsp = (char*)d_ws;
  size_t off = 0;
  auto alloc = [&](size_t bytes) {
    char* r = wsp + off;
    off = (off + bytes + 255) & ~(size_t)255;
    return r;
  };
  const size_t MB = 1024 * 1024;
  unsigned short* w_ca_vw = (unsigned short*)alloc(1024 * 1024 * 2);
  unsigned short* w_ca_ow = (unsigned short*)alloc(512 * 1024 * 2);
  unsigned short* w_ca_aw = (unsigned short*)alloc(256 * 1024 * 2);
  unsigned short* w_ca_pw = (unsigned short*)alloc(1024 * 1024 * 2);
  unsigned short* w_sa_vw = (unsigned short*)alloc(1024 * 1024 * 2);
  unsigned short* w_sa_ow = (unsigned short*)alloc(128 * 1024 * 2);
  unsigned short* w_sa_aw = (unsigned short*)alloc(64 * 1024 * 2);
  unsigned short* w_sa_pw = (unsigned short*)alloc(1024 * 1024 * 2);
  (void)w_ca_aw; (void)w_sa_ow; (void)w_sa_aw;
  char* R1 = alloc(32 * MB);  // f_ln bf16 | attn f32 + attn1 bf16 + samp_sa bf16
  char* R2 = alloc(32 * MB);  // val_ca bf16 | val_sa bf16
  char* R3 = alloc(8 * MB);   // q_ln bf16 | samp_ca bf16
  char* R4 = alloc(8 * MB);   // off_ca f32 | off_sa f32 + attw_sa f32
  char* R5 = alloc(4 * MB);   // attw_ca f32 (raw logits; softmax fused)

  unsigned short* f_ln    = (unsigned short*)R1;
  float*          attn    = (float*)R1;
  unsigned short* attn1   = (unsigned short*)(R1 + 16 * MB);
  unsigned short* samp_sa = (unsigned short*)(R1 + 24 * MB);
  unsigned short* val_ca  = (unsigned short*)R2;
  unsigned short* val_sa  = (unsigned short*)R2;
  unsigned short* q_ln    = (unsigned short*)R3;
  unsigned short* samp_ca = (unsigned short*)R3;
  float*          off_ca  = (float*)R4;
  float*          off_sa  = (float*)R4;
  float*          attw_sa = (float*)(R4 + 4 * MB);
  float*          attw_ca = (float*)R5;

  // ---- 1. merged weight conversion ----
  CvtArgs ca;
  ca.src[0] = ca_vw; ca.src[1] = ca_ow; ca.src[2] = ca_aw; ca.src[3] = ca_pw;
  ca.src[4] = sa_vw; ca.src[5] = sa_ow; ca.src[6] = sa_aw; ca.src[7] = sa_pw;
  ca.dst = w_ca_vw;
  const int sizes4[8] = {262144, 131072, 65536, 262144, 262144, 32768, 16384, 262144};
  ca.off4[0] = 0;
  for (int i = 0; i < 8; ++i) ca.off4[i + 1] = ca.off4[i] + sizes4[i];
  f2bf_multi<<<ca.off4[8] / 256, 256, 0, stream>>>(ca);

  // ---- 2. LayerNorms (feat x4 + query in one launch) ----
  ln5_kernel<<<20480, 256, 0, stream>>>(src[0], src[1], src[2], src[3],
                                        fn_g, fn_b, qn_g, qn_b, f_ln, q_ln);

  auto mkP = [](const unsigned short* A, const unsigned short* W, void* C,
                const float* b0, int M, int N, int K, int tilesM) {
    GemmP p{}; p.A = A; p.W = W; p.C = C; p.b0 = b0;
    p.M = M; p.N = N; p.K = K; p.tilesM = tilesM;
    return p;
  };

  // ---- 3. CA: value GEMM + fused off/attw GEMM ----
  gemm_v3<128, 128, 1><<<128 * 8, 256, 0, stream>>>(
      mkP(f_ln, w_ca_vw, val_ca, ca_vb, 16384, 1024, 1024, 128));
  {
    GemmP p = mkP(q_ln, w_ca_ow, off_ca, ca_ob, 4096, 768, 1024, 64);
    p.C1 = attw_ca; p.b1 = ca_ab;
    gemm_v3<64, 128, 2><<<64 * 6, 256, 0, stream>>>(p);
  }

  // ---- 4. CA sampling + projection ----
  ms_sample_fused<4><<<4096, 256, 0, stream>>>(val_ca, off_ca, attw_ca, samp_ca);
  gemm_v3<64, 128, 0><<<64 * 8, 256, 0, stream>>>(
      mkP(samp_ca, w_ca_pw, attn, ca_pb, 4096, 1024, 1024, 64));

  // ---- 5. SA branch ----
  ln_bf16_kernel<<<4096, 256, 0, stream>>>(attn, n1_g, n1_b, attn1);
  {
    GemmP p = mkP(attn1, w_sa_vw, val_sa, sa_vb, 4096, 1216, 1024, 64);
    p.C1 = off_sa; p.b1 = sa_ob; p.C2 = attw_sa; p.b2 = sa_ab;
    gemm_v3<64, 128, 3><<<64 * 10, 256, 0, stream>>>(p);
  }
  ms_sample_fused<1><<<4096, 256, 0, stream>>>(val_sa, off_sa, attw_sa, samp_sa);
  {
    GemmP p = mkP(samp_sa, w_sa_pw, d_out, sa_pb, 4096, 1024, 1024, 64);
    p.src3 = src[3]; p.g1 = gamma1; p.g2 = gamma2; p.attnp = attn;
    gemm_v3<64, 128, 4><<<64 * 8, 256, 0, stream>>>(p);
  }
}

// Round 5
// 356.967 us; speedup vs baseline: 1.9287x; 1.0271x over previous
//
#include <hip/hip_runtime.h>

// ---------------------------------------------------------------------------
// MSCrossAttnBlock on MI355X (gfx950).
// B=4, E=32, LQ=1024, D=1024, NH=16, DH=64, NP=4. All levels are 32x32.
// R4: wave-per-row LayerNorm (no barriers/LDS); CA val + off/attw GEMMs merged
//     into one 1216-block dispatch (dynamic LDS shared across paths).
//     9 dispatches.
// ---------------------------------------------------------------------------

#define DEV __device__ __forceinline__

typedef float f32x4 __attribute__((ext_vector_type(4)));
typedef __bf16 bf16x8 __attribute__((ext_vector_type(8)));

DEV unsigned short f2bf(float f) {
  union { float f; unsigned u; } a; a.f = f;
  unsigned r = a.u + 0x7fffu + ((a.u >> 16) & 1u);
  return (unsigned short)(r >> 16);
}
DEV float bf2f(unsigned short h) {
  union { unsigned u; float f; } a; a.u = ((unsigned)h) << 16;
  return a.f;
}

// ---------------- merged weight fp32 -> bf16 conversion --------------------
struct CvtArgs {
  const float* src[8];
  unsigned short* dst;
  int off4[9];  // prefix sums, float4 units
};

__global__ __launch_bounds__(256) void f2bf_multi(CvtArgs a) {
  int i = blockIdx.x * 256 + threadIdx.x;  // float4 index, exact grid
  int seg = 0;
  #pragma unroll
  for (int s = 1; s < 8; ++s) seg += (i >= a.off4[s]) ? 1 : 0;
  const float4 v = ((const float4*)a.src[seg])[i - a.off4[seg]];
  unsigned short* o = a.dst + (size_t)i * 4;
  o[0] = f2bf(v.x); o[1] = f2bf(v.y); o[2] = f2bf(v.z); o[3] = f2bf(v.w);
}

// ---------------- LayerNorm: one WAVE per row (no barriers, no LDS) --------
// Lane holds 16 floats (4x float4, stride-64 coalesced). Butterfly reduce.
DEV void ln_row_wave(const float* __restrict__ xr, const float* __restrict__ g,
                     const float* __restrict__ b,
                     unsigned short* __restrict__ op_row) {
  const int lane = threadIdx.x & 63;
  float4 v[4];
  float s = 0.f, s2 = 0.f;
  #pragma unroll
  for (int j = 0; j < 4; ++j) {
    v[j] = ((const float4*)xr)[lane + 64 * j];
    s  += v[j].x + v[j].y + v[j].z + v[j].w;
    s2 += v[j].x*v[j].x + v[j].y*v[j].y + v[j].z*v[j].z + v[j].w*v[j].w;
  }
  #pragma unroll
  for (int o = 32; o; o >>= 1) { s += __shfl_xor(s, o); s2 += __shfl_xor(s2, o); }
  const float mean = s * (1.f / 1024.f);
  const float rstd = rsqrtf(s2 * (1.f / 1024.f) - mean * mean + 1e-6f);
  #pragma unroll
  for (int j = 0; j < 4; ++j) {
    float4 gg = ((const float4*)g)[lane + 64 * j];
    float4 bb = ((const float4*)b)[lane + 64 * j];
    ushort4 r;
    r.x = f2bf((v[j].x - mean) * rstd * gg.x + bb.x);
    r.y = f2bf((v[j].y - mean) * rstd * gg.y + bb.y);
    r.z = f2bf((v[j].z - mean) * rstd * gg.z + bb.z);
    r.w = f2bf((v[j].w - mean) * rstd * gg.w + bb.w);
    ((ushort4*)op_row)[lane + 64 * j] = r;
  }
}

__global__ __launch_bounds__(256) void ln_wave_kernel(
    const float* __restrict__ x, const float* __restrict__ g,
    const float* __restrict__ b, unsigned short* __restrict__ out) {
  int row = blockIdx.x * 4 + (threadIdx.x >> 6);
  ln_row_wave(x + (size_t)row * 1024, g, b, out + (size_t)row * 1024);
}

// rows 0..16383: feat levels -> f_ln (B,4,1024,1024); rows 16384..20479: q_ln.
__global__ __launch_bounds__(256) void ln5_wave_kernel(
    const float* __restrict__ s0, const float* __restrict__ s1,
    const float* __restrict__ s2, const float* __restrict__ s3,
    const float* __restrict__ fg, const float* __restrict__ fb,
    const float* __restrict__ qg, const float* __restrict__ qb,
    unsigned short* __restrict__ f_out, unsigned short* __restrict__ q_out) {
  int row = blockIdx.x * 4 + (threadIdx.x >> 6);  // 0..20479
  if (row < 16384) {
    int l = row >> 12, inner = row & 4095;
    const float* srcs[4] = {s0, s1, s2, s3};
    int orow = (inner >> 10) * 4096 + l * 1024 + (inner & 1023);
    ln_row_wave(srcs[l] + (size_t)inner * 1024, fg, fb,
                f_out + (size_t)orow * 1024);
  } else {
    int inner = row - 16384;
    ln_row_wave(s3 + (size_t)inner * 1024, qg, qb,
                q_out + (size_t)inner * 1024);
  }
}

// ---------------- bf16 MFMA GEMM, VGPR staging + swizzled LDS --------------
// C[M,N] = A[M,K] @ W[N,K]^T (+bias). BK=64 as two 32-k sub-tiles.
// LDS layout measured conflict-free (R2/R3: SQ_LDS_BANK_CONFLICT = 0).
// EPI: 0=f32, 1=bf16, 2=CA split(off512|attw256), 3=SA split(val1024 bf16|
//      off128 f32|attw64 f32), 4=final combine -> d_out.
struct GemmP {
  const unsigned short* A; const unsigned short* W;
  void* C; void* C1; void* C2;
  const float* b0; const float* b1; const float* b2;
  const float* src3; const float* g1; const float* g2; const float* attnp;
  int M, N, K, tilesM;
};

template <int BM, int BN, int EPI>
DEV void gemm_body(const GemmP& P, int id, unsigned short* sA,
                   unsigned short* sB) {
  constexpr int WMT = BM / 2, WNT = BN / 2;
  constexpr int MF = WMT / 16, NF = WNT / 16;
  constexpr int PA = BM / 64, PB = BN / 64;    // granule passes per sub-tile
  const int tid = threadIdx.x;
  const int wave = tid >> 6, lane = tid & 63;
  const int wm = (wave & 1) * WMT, wn = (wave >> 1) * WNT;
  const int m0 = (id % P.tilesM) * BM;
  const int n0 = (id / P.tilesM) * BN;
  const int lq = lane >> 4, lm = lane & 15;
  const int r16 = lane >> 2;                    // row within granule
  const int cst = lane & 3;                     // slot within row
  const int csrc = cst ^ ((r16 >> 1) & 3);      // global k-chunk for slot
  const int aslot = lq ^ ((lm >> 1) & 3);       // read slot for chunk lq

  f32x4 acc[MF][NF] = {};
  bf16x8 ald[2][PA], bld[2][PB];

  #pragma unroll 1
  for (int k0 = 0; k0 < P.K; k0 += 64) {
    #pragma unroll
    for (int s = 0; s < 2; ++s) {
      #pragma unroll
      for (int p = 0; p < PA; ++p) {
        int grow = m0 + (wave + 4 * p) * 16 + r16;
        ald[s][p] = *(const bf16x8*)(P.A + (size_t)grow * P.K + k0 + s * 32 + csrc * 8);
      }
      #pragma unroll
      for (int p = 0; p < PB; ++p) {
        int grow = min(n0 + (wave + 4 * p) * 16 + r16, P.N - 1);
        bld[s][p] = *(const bf16x8*)(P.W + (size_t)grow * P.K + k0 + s * 32 + csrc * 8);
      }
    }
    __syncthreads();  // prev iteration's LDS reads complete
    #pragma unroll
    for (int s = 0; s < 2; ++s) {
      #pragma unroll
      for (int p = 0; p < PA; ++p)
        *(bf16x8*)(sA + s * BM * 32 + (wave + 4 * p) * 512 + (r16 * 4 + cst) * 8) = ald[s][p];
      #pragma unroll
      for (int p = 0; p < PB; ++p)
        *(bf16x8*)(sB + s * BN * 32 + (wave + 4 * p) * 512 + (r16 * 4 + cst) * 8) = bld[s][p];
    }
    __syncthreads();
    #pragma unroll
    for (int s = 0; s < 2; ++s) {
      bf16x8 af[MF], bfr[NF];
      #pragma unroll
      for (int mi = 0; mi < MF; ++mi)
        af[mi] = *(const bf16x8*)(sA + s * BM * 32 + ((wm >> 4) + mi) * 512 + lm * 32 + aslot * 8);
      #pragma unroll
      for (int ni = 0; ni < NF; ++ni)
        bfr[ni] = *(const bf16x8*)(sB + s * BN * 32 + ((wn >> 4) + ni) * 512 + lm * 32 + aslot * 8);
      #pragma unroll
      for (int mi = 0; mi < MF; ++mi)
        #pragma unroll
        for (int ni = 0; ni < NF; ++ni)
          acc[mi][ni] = __builtin_amdgcn_mfma_f32_16x16x32_bf16(
              af[mi], bfr[ni], acc[mi][ni], 0, 0, 0);
    }
  }

  #pragma unroll
  for (int mi = 0; mi < MF; ++mi) {
    #pragma unroll
    for (int ni = 0; ni < NF; ++ni) {
      const int col = n0 + wn + ni * 16 + lm;
      #pragma unroll
      for (int r2 = 0; r2 < 4; ++r2) {
        const int row = m0 + wm + mi * 16 + lq * 4 + r2;
        float v = acc[mi][ni][r2];
        if constexpr (EPI == 0) {
          ((float*)P.C)[(size_t)row * 1024 + col] = v + P.b0[col];
        } else if constexpr (EPI == 1) {
          ((unsigned short*)P.C)[(size_t)row * 1024 + col] = f2bf(v + P.b0[col]);
        } else if constexpr (EPI == 2) {
          if (col < 512)
            ((float*)P.C)[(size_t)row * 512 + col] = v + P.b0[col];
          else
            ((float*)P.C1)[(size_t)row * 256 + col - 512] = v + P.b1[col - 512];
        } else if constexpr (EPI == 3) {
          if (col < 1024)
            ((unsigned short*)P.C)[(size_t)row * 1024 + col] = f2bf(v + P.b0[col]);
          else if (col < 1152)
            ((float*)P.C1)[(size_t)row * 128 + col - 1024] = v + P.b1[col - 1024];
          else if (col < 1216)
            ((float*)P.C2)[(size_t)row * 64 + col - 1152] = v + P.b2[col - 1152];
        } else {  // EPI == 4: out = src3 + g1*(attn + g2*(v+b))
          size_t i = (size_t)row * 1024 + col;
          float vv = v + P.b0[col];
          ((float*)P.C)[i] = P.src3[i] + P.g1[col] * (P.attnp[i] + P.g2[col] * vv);
        }
      }
    }
  }
}

template <int BM, int BN, int EPI>
__global__ __launch_bounds__(256) void gemm_v3(GemmP P) {
  extern __shared__ __align__(16) unsigned short smem[];
  gemm_body<BM, BN, EPI>(P, blockIdx.x, smem, smem + BM * 64);
}

// merged CA dispatch: blocks [0,split) = val GEMM (EPI1), rest = off/attw (EPI2)
template <int BM, int BN>
__global__ __launch_bounds__(256) void gemm_dual(GemmP Pv, GemmP Po, int split) {
  extern __shared__ __align__(16) unsigned short smem[];
  if ((int)blockIdx.x < split)
    gemm_body<BM, BN, 1>(Pv, blockIdx.x, smem, smem + BM * 64);
  else
    gemm_body<BM, BN, 2>(Po, blockIdx.x - split, smem, smem + BM * 64);
}

// ---------------- fused softmax + MS-deform bilinear sampling --------------
template <int NLEV>
__global__ __launch_bounds__(256) void ms_sample_fused(
    const unsigned short* __restrict__ value, const float* __restrict__ off,
    const float* __restrict__ logits, unsigned short* __restrict__ out) {
  const int nq = blockIdx.x;               // n*1024 + q
  const int wave = threadIdx.x >> 6, lane = threadIdx.x & 63;
  const int h = (wave << 2) + (lane >> 4);
  const int c = (lane & 15) << 2;          // channel base (0..60)
  const int q = nq & 1023, n = nq >> 10;
  const float* offp = off + ((size_t)nq * 16 + h) * (NLEV * 8);
  const float* lgp  = logits + ((size_t)nq * 16 + h) * (NLEV * 4);

  float lg[NLEV * 4];
  #pragma unroll
  for (int i = 0; i < NLEV; ++i) {
    float4 v = ((const float4*)lgp)[i];
    lg[4*i] = v.x; lg[4*i+1] = v.y; lg[4*i+2] = v.z; lg[4*i+3] = v.w;
  }
  float mx = lg[0];
  #pragma unroll
  for (int i = 1; i < NLEV * 4; ++i) mx = fmaxf(mx, lg[i]);
  float ssum = 0.f;
  #pragma unroll
  for (int i = 0; i < NLEV * 4; ++i) { lg[i] = __expf(lg[i] - mx); ssum += lg[i]; }
  const float inv = 1.f / ssum;

  const float fqx = (float)(q & 31), fqy = (float)(q >> 5);
  float a0 = 0.f, a1 = 0.f, a2 = 0.f, a3 = 0.f;

  #pragma unroll
  for (int l = 0; l < NLEV; ++l) {
    const unsigned short* vl =
        value + ((size_t)(n * NLEV + l) << 20) + h * 64 + c;
    #pragma unroll
    for (int p = 0; p < 4; ++p) {
      float2 o2 = ((const float2*)offp)[l * 4 + p];
      float aw = lg[l * 4 + p] * inv;
      float xx = fqx + o2.x, yy = fqy + o2.y;
      float xf = floorf(xx), yf = floorf(yy);
      float fx = xx - xf, fy = yy - yf;
      int ix = (int)xf, iy = (int)yf;
      int ix1 = ix + 1, iy1 = iy + 1;
      float vx0 = ((unsigned)ix  < 32u) ? 1.f : 0.f;
      float vx1 = ((unsigned)ix1 < 32u) ? 1.f : 0.f;
      float vy0 = ((unsigned)iy  < 32u) ? 1.f : 0.f;
      float vy1 = ((unsigned)iy1 < 32u) ? 1.f : 0.f;
      int cx0 = min(max(ix, 0), 31), cx1 = min(max(ix1, 0), 31);
      int cy0 = min(max(iy, 0), 31), cy1 = min(max(iy1, 0), 31);
      float w00 = (1.f - fx) * (1.f - fy) * vx0 * vy0 * aw;
      float w01 = fx * (1.f - fy) * vx1 * vy0 * aw;
      float w10 = (1.f - fx) * fy * vx0 * vy1 * aw;
      float w11 = fx * fy * vx1 * vy1 * aw;
      ushort4 u00 = *(const ushort4*)(vl + ((size_t)(cy0 * 32 + cx0) << 10));
      ushort4 u01 = *(const ushort4*)(vl + ((size_t)(cy0 * 32 + cx1) << 10));
      ushort4 u10 = *(const ushort4*)(vl + ((size_t)(cy1 * 32 + cx0) << 10));
      ushort4 u11 = *(const ushort4*)(vl + ((size_t)(cy1 * 32 + cx1) << 10));
      a0 += w00 * bf2f(u00.x) + w01 * bf2f(u01.x) + w10 * bf2f(u10.x) + w11 * bf2f(u11.x);
      a1 += w00 * bf2f(u00.y) + w01 * bf2f(u01.y) + w10 * bf2f(u10.y) + w11 * bf2f(u11.y);
      a2 += w00 * bf2f(u00.z) + w01 * bf2f(u01.z) + w10 * bf2f(u10.z) + w11 * bf2f(u11.z);
      a3 += w00 * bf2f(u00.w) + w01 * bf2f(u01.w) + w10 * bf2f(u10.w) + w11 * bf2f(u11.w);
    }
  }
  ushort4 r;
  r.x = f2bf(a0); r.y = f2bf(a1); r.z = f2bf(a2); r.w = f2bf(a3);
  *(ushort4*)(out + ((size_t)nq * 16 + h) * 64 + c) = r;
}

// ---------------------------------------------------------------------------
extern "C" void kernel_launch(void* const* d_in, const int* in_sizes, int n_in,
                              void* d_out, int out_size, void* d_ws,
                              size_t ws_size, hipStream_t stream) {
  (void)in_sizes; (void)n_in; (void)out_size; (void)ws_size;
  const float* src[4] = {(const float*)d_in[0], (const float*)d_in[1],
                         (const float*)d_in[2], (const float*)d_in[3]};
  const float* qn_g = (const float*)d_in[4];
  const float* qn_b = (const float*)d_in[5];
  const float* fn_g = (const float*)d_in[6];
  const float* fn_b = (const float*)d_in[7];
  const float* n1_g = (const float*)d_in[8];
  const float* n1_b = (const float*)d_in[9];
  const float* gamma1 = (const float*)d_in[10];
  const float* gamma2 = (const float*)d_in[11];
  const float* ca_vw = (const float*)d_in[12];
  const float* ca_vb = (const float*)d_in[13];
  const float* ca_ow = (const float*)d_in[14];
  const float* ca_ob = (const float*)d_in[15];
  const float* ca_aw = (const float*)d_in[16];
  const float* ca_ab = (const float*)d_in[17];
  const float* ca_pw = (const float*)d_in[18];
  const float* ca_pb = (const float*)d_in[19];
  const float* sa_vw = (const float*)d_in[20];
  const float* sa_vb = (const float*)d_in[21];
  const float* sa_ow = (const float*)d_in[22];
  const float* sa_ob = (const float*)d_in[23];
  const float* sa_aw = (const float*)d_in[24];
  const float* sa_ab = (const float*)d_in[25];
  const float* sa_pw = (const float*)d_in[26];
  const float* sa_pb = (const float*)d_in[27];

  // ---- workspace layout ----
  char* wsp = (char*)d_ws;
  size_t off = 0;
  auto alloc = [&](size_t bytes) {
    char* r = wsp + off;
    off = (off + bytes + 255) & ~(size_t)255;
    return r;
  };
  const size_t MB = 1024 * 1024;
  unsigned short* w_ca_vw = (unsigned short*)alloc(1024 * 1024 * 2);
  unsigned short* w_ca_ow = (unsigned short*)alloc(512 * 1024 * 2);
  unsigned short* w_ca_aw = (unsigned short*)alloc(256 * 1024 * 2);
  unsigned short* w_ca_pw = (unsigned short*)alloc(1024 * 1024 * 2);
  unsigned short* w_sa_vw = (unsigned short*)alloc(1024 * 1024 * 2);
  unsigned short* w_sa_ow = (unsigned short*)alloc(128 * 1024 * 2);
  unsigned short* w_sa_aw = (unsigned short*)alloc(64 * 1024 * 2);
  unsigned short* w_sa_pw = (unsigned short*)alloc(1024 * 1024 * 2);
  (void)w_ca_aw; (void)w_sa_ow; (void)w_sa_aw;
  char* R1 = alloc(32 * MB);  // f_ln bf16 | attn f32 + attn1 bf16 + samp_sa bf16
  char* R2 = alloc(32 * MB);  // val_ca bf16 | val_sa bf16
  char* R3 = alloc(8 * MB);   // q_ln bf16 | samp_ca bf16
  char* R4 = alloc(8 * MB);   // off_ca f32 | off_sa f32 + attw_sa f32
  char* R5 = alloc(4 * MB);   // attw_ca f32 (raw logits; softmax fused)

  unsigned short* f_ln    = (unsigned short*)R1;
  float*          attn    = (float*)R1;
  unsigned short* attn1   = (unsigned short*)(R1 + 16 * MB);
  unsigned short* samp_sa = (unsigned short*)(R1 + 24 * MB);
  unsigned short* val_ca  = (unsigned short*)R2;
  unsigned short* val_sa  = (unsigned short*)R2;
  unsigned short* q_ln    = (unsigned short*)R3;
  unsigned short* samp_ca = (unsigned short*)R3;
  float*          off_ca  = (float*)R4;
  float*          off_sa  = (float*)R4;
  float*          attw_sa = (float*)(R4 + 4 * MB);
  float*          attw_ca = (float*)R5;

  // ---- 1. merged weight conversion ----
  CvtArgs ca;
  ca.src[0] = ca_vw; ca.src[1] = ca_ow; ca.src[2] = ca_aw; ca.src[3] = ca_pw;
  ca.src[4] = sa_vw; ca.src[5] = sa_ow; ca.src[6] = sa_aw; ca.src[7] = sa_pw;
  ca.dst = w_ca_vw;
  const int sizes4[8] = {262144, 131072, 65536, 262144, 262144, 32768, 16384, 262144};
  ca.off4[0] = 0;
  for (int i = 0; i < 8; ++i) ca.off4[i + 1] = ca.off4[i] + sizes4[i];
  f2bf_multi<<<ca.off4[8] / 256, 256, 0, stream>>>(ca);

  // ---- 2. LayerNorms (feat x4 + query; wave per row) ----
  ln5_wave_kernel<<<5120, 256, 0, stream>>>(src[0], src[1], src[2], src[3],
                                            fn_g, fn_b, qn_g, qn_b, f_ln, q_ln);

  auto mkP = [](const unsigned short* A, const unsigned short* W, void* C,
                const float* b0, int M, int N, int K, int tilesM) {
    GemmP p{}; p.A = A; p.W = W; p.C = C; p.b0 = b0;
    p.M = M; p.N = N; p.K = K; p.tilesM = tilesM;
    return p;
  };

  // ---- 3. CA: merged value + off/attw GEMM (one dispatch) ----
  {
    GemmP pv = mkP(f_ln, w_ca_vw, val_ca, ca_vb, 16384, 1024, 1024, 128);
    GemmP po = mkP(q_ln, w_ca_ow, off_ca, ca_ob, 4096, 768, 1024, 32);
    po.C1 = attw_ca; po.b1 = ca_ab;
    gemm_dual<128, 128><<<1024 + 192, 256, 65536 / 2, stream>>>(pv, po, 1024);
  }

  // ---- 4. CA sampling + projection ----
  ms_sample_fused<4><<<4096, 256, 0, stream>>>(val_ca, off_ca, attw_ca, samp_ca);
  gemm_v3<64, 128, 0><<<64 * 8, 256, (64 + 128) * 64 * 2, stream>>>(
      mkP(samp_ca, w_ca_pw, attn, ca_pb, 4096, 1024, 1024, 64));

  // ---- 5. SA branch ----
  ln_wave_kernel<<<1024, 256, 0, stream>>>(attn, n1_g, n1_b, attn1);
  {
    GemmP p = mkP(attn1, w_sa_vw, val_sa, sa_vb, 4096, 1216, 1024, 64);
    p.C1 = off_sa; p.b1 = sa_ob; p.C2 = attw_sa; p.b2 = sa_ab;
    gemm_v3<64, 128, 3><<<64 * 10, 256, (64 + 128) * 64 * 2, stream>>>(p);
  }
  ms_sample_fused<1><<<4096, 256, 0, stream>>>(val_sa, off_sa, attw_sa, samp_sa);
  {
    GemmP p = mkP(samp_sa, w_sa_pw, d_out, sa_pb, 4096, 1024, 1024, 64);
    p.src3 = src[3]; p.g1 = gamma1; p.g2 = gamma2; p.attnp = attn;
    gemm_v3<64, 128, 4><<<64 * 8, 256, (64 + 128) * 64 * 2, stream>>>(p);
  }
}